// Round 6
// baseline (522.640 us; speedup 1.0000x reference)
//
#include <hip/hip_runtime.h>
#include <hip/hip_bf16.h>
#include <float.h>

#define NN 2048
#define HH 16
#define DDIM 64
#define QB 64   // q-rows per block = 4 waves x 16 rows
#define KB 64
#define PARTF 4224            // floats per partial: 64x64 O + 64 m + 64 l
#define WS_NEED (1024ull * PARTF * 4ull)

typedef __bf16 bf16x8 __attribute__((ext_vector_type(8)));
typedef __bf16 bf16x4 __attribute__((ext_vector_type(4)));
typedef float f32x4 __attribute__((ext_vector_type(4)));

// Raw barrier: LDS-writes visible; outstanding GLOBAL prefetch loads stay in flight.
__device__ __forceinline__ void barw() {
  __builtin_amdgcn_sched_barrier(0);
  asm volatile("s_waitcnt lgkmcnt(0)" ::: "memory");
  __builtin_amdgcn_s_barrier();
  __builtin_amdgcn_sched_barrier(0);
}

__device__ __forceinline__ unsigned pack2(float a, float b) {
  union { __bf16 h[2]; unsigned u; } x;
  x.h[0] = (__bf16)a; x.h[1] = (__bf16)b;
  return x.u;
}

// ============================================================================
// R6 main: R4 block structure (4 waves, swapped-QK^T, row-owning waves) but
// each block handles HALF of its q-tile's kv range -> 1024 blocks, ~3/CU
// resident with refill. Writes unnormalized (O, m, l) partials to ws.
// x: qt = 31-(x>>1) (big first), half = x&1.
// ============================================================================
__global__ __launch_bounds__(256, 3) void attend_part(
    const float* __restrict__ qg, const float* __restrict__ kg,
    const float* __restrict__ vg, const unsigned int* __restrict__ maskw,
    const float* __restrict__ biasg, const float* __restrict__ prevg,
    float* __restrict__ opart)
{
  __shared__ char ksh[KB * 128]   __attribute__((aligned(16))); // [kv][d] bf16, XOR-swizzled
  __shared__ char vsh[DDIM * 128] __attribute__((aligned(16))); // [d][kv] bf16, XOR-swizzled

  const int t    = threadIdx.x;
  const int lane = t & 63;
  const int w    = t >> 6;
  const int x    = blockIdx.x;   // 0..63
  const int h    = blockIdx.y;
  const int qt   = 31 - (x >> 1);
  const int half = x & 1;
  const int T    = qt + 1;
  const int mid  = (T + 1) >> 1;
  const int lo   = half ? mid : 0;
  const int hi   = half ? T : mid;
  const int qrow0 = qt * QB;

  // --- mask element-width detection: 4-byte (int/float bool) vs 1-byte ---
  unsigned int mwrd = maskw[t & 255];
  const int mask4 = __syncthreads_and(mwrd == 0u || mwrd == 1u || mwrd == 0x3F800000u);

  const int llo = lane & 15;
  const int lhi = lane >> 4;
  const int qrow_g = qrow0 + w * 16 + llo;   // this lane's q-row

  // --- Q fragments (B operand), scale 1/8 folded in ---
  bf16x8 aq[2];
  {
    const float* qp = qg + ((size_t)(h * NN + qrow_g)) * DDIM + lhi * 8;
#pragma unroll
    for (int ks = 0; ks < 2; ++ks) {
      float4 f0 = *(const float4*)(qp + ks * 32);
      float4 f1 = *(const float4*)(qp + ks * 32 + 4);
      bf16x8 a;
      a[0] = (__bf16)(f0.x * 0.125f); a[1] = (__bf16)(f0.y * 0.125f);
      a[2] = (__bf16)(f0.z * 0.125f); a[3] = (__bf16)(f0.w * 0.125f);
      a[4] = (__bf16)(f1.x * 0.125f); a[5] = (__bf16)(f1.y * 0.125f);
      a[6] = (__bf16)(f1.z * 0.125f); a[7] = (__bf16)(f1.w * 0.125f);
      aq[ks] = a;
    }
  }

  f32x4 oacc[4];   // O^T frags: oacc[df][r] = O[q=llo-row][d=df*16+lhi*4+r]
#pragma unroll
  for (int i = 0; i < 4; ++i) { f32x4 z = {0.f, 0.f, 0.f, 0.f}; oacc[i] = z; }
  float m_r = -FLT_MAX, l_r = 0.f;

  // ---- prefetch registers ----
  float4 kpre[4], vpre[4];
  float4 ppre[4], bpre[4];
  uint4  mpre[4];

  auto issueKV = [&](int kv0) {
#pragma unroll
    for (int e = 0; e < 4; ++e) {
      const int f4  = t + e * 256;
      const int row = f4 >> 4;
      const int cb  = (f4 & 15) * 4;
      const size_t gofs = ((size_t)(h * NN + kv0 + row)) * DDIM + cb;
      kpre[e] = *(const float4*)(kg + gofs);
      vpre[e] = *(const float4*)(vg + gofs);
    }
  };
  auto issuePB = [&](int kv0) {
#pragma unroll
    for (int kf = 0; kf < 4; ++kf) {
      const int col = kv0 + kf * 16 + lhi * 4;
      const size_t base = ((size_t)(h * NN) + qrow_g) * NN + col;
      ppre[kf] = *(const float4*)(prevg + base);
      bpre[kf] = *(const float4*)(biasg + base);
      const size_t midx = (size_t)qrow_g * NN + col;
      if (mask4) {
        mpre[kf] = *(const uint4*)(maskw + midx);
      } else {
        mpre[kf].x = *(const unsigned int*)((const unsigned char*)maskw + midx);
      }
    }
  };

  if (lo < hi) { issueKV(lo * KB); issuePB(lo * KB); }

  for (int tt = lo; tt < hi; ++tt) {
    const int kv0 = tt * KB;
    // ---- phase 1: stage K (row-major) and V (transposed), f32->bf16, swizzled ----
#pragma unroll
    for (int e = 0; e < 4; ++e) {
      const int f4  = t + e * 256;
      const int row = f4 >> 4;
      const int cb  = (f4 & 15) * 4;
      float4 kf = kpre[e];
      bf16x4 kb4;
      kb4[0] = (__bf16)kf.x; kb4[1] = (__bf16)kf.y;
      kb4[2] = (__bf16)kf.z; kb4[3] = (__bf16)kf.w;
      *(bf16x4*)(ksh + (((row << 7) + (cb << 1)) ^ ((row & 7) << 4))) = kb4;
      float4 vf = vpre[e];
      *(__bf16*)(vsh + ((((cb + 0) << 7) + (row << 1)) ^ (((cb + 0) & 7) << 4))) = (__bf16)vf.x;
      *(__bf16*)(vsh + ((((cb + 1) << 7) + (row << 1)) ^ (((cb + 1) & 7) << 4))) = (__bf16)vf.y;
      *(__bf16*)(vsh + ((((cb + 2) << 7) + (row << 1)) ^ (((cb + 2) & 7) << 4))) = (__bf16)vf.z;
      *(__bf16*)(vsh + ((((cb + 3) << 7) + (row << 1)) ^ (((cb + 3) & 7) << 4))) = (__bf16)vf.w;
    }
    // keep current tile's softmax operands
    float4 pc[4], bc[4]; uint4 mc[4];
#pragma unroll
    for (int kf = 0; kf < 4; ++kf) { pc[kf] = ppre[kf]; bc[kf] = bpre[kf]; mc[kf] = mpre[kf]; }
    // issue next tile's loads (fly across the raw barriers)
    if (tt + 1 < hi) { issueKV(kv0 + KB); issuePB(kv0 + KB); }
    barw();

    // ---- QK^T swapped: S^T[kv][q], each lane: q=llo-row, 16 kv values ----
    f32x4 s[4];
#pragma unroll
    for (int kf = 0; kf < 4; ++kf) { f32x4 z = {0.f, 0.f, 0.f, 0.f}; s[kf] = z; }
#pragma unroll
    for (int ks = 0; ks < 2; ++ks) {
#pragma unroll
      for (int kf = 0; kf < 4; ++kf) {
        const int kvr = kf * 16 + llo;
        bf16x8 ak = *(const bf16x8*)(ksh + (((kvr << 7) + ((ks * 32 + lhi * 8) << 1)) ^ ((kvr & 7) << 4)));
        s[kf] = __builtin_amdgcn_mfma_f32_16x16x32_bf16(ak, aq[ks], s[kf], 0, 0, 0);
      }
    }

    // ---- softmax, fully in-register (row = q = llo; 4 lanes/row via xor16/32) ----
    float p[4][4];
    float pmax = -FLT_MAX;
#pragma unroll
    for (int kf = 0; kf < 4; ++kf) {
      float pa[4] = {pc[kf].x, pc[kf].y, pc[kf].z, pc[kf].w};
      float ba[4] = {bc[kf].x, bc[kf].y, bc[kf].z, bc[kf].w};
      unsigned mb[4];
      if (mask4) { mb[0] = mc[kf].x; mb[1] = mc[kf].y; mb[2] = mc[kf].z; mb[3] = mc[kf].w; }
      else {
        mb[0] = mc[kf].x & 0xffu; mb[1] = (mc[kf].x >> 8) & 0xffu;
        mb[2] = (mc[kf].x >> 16) & 0xffu; mb[3] = mc[kf].x >> 24;
      }
#pragma unroll
      for (int r = 0; r < 4; ++r) {
        const int j = kv0 + kf * 16 + lhi * 4 + r;
        float sv = s[kf][r] + pa[r] + ba[r];
        if (j > qrow_g || mb[r] == 0u) sv = -FLT_MAX;
        p[kf][r] = sv;
        pmax = fmaxf(pmax, sv);
      }
    }
    pmax = fmaxf(pmax, __shfl_xor(pmax, 16));
    pmax = fmaxf(pmax, __shfl_xor(pmax, 32));
    const float mnew = fmaxf(m_r, pmax);
    const float resc = __expf(m_r - mnew);   // exp(0)=1 when both -FLT_MAX (finite)
    float psum = 0.f;
#pragma unroll
    for (int kf = 0; kf < 4; ++kf)
#pragma unroll
      for (int r = 0; r < 4; ++r) {
        float e = __expf(p[kf][r] - mnew);
        p[kf][r] = e;
        psum += e;
      }
    psum += __shfl_xor(psum, 16);
    psum += __shfl_xor(psum, 32);
    l_r = l_r * resc + psum;
    m_r = mnew;
#pragma unroll
    for (int df = 0; df < 4; ++df) {
      oacc[df][0] *= resc; oacc[df][1] *= resc;
      oacc[df][2] *= resc; oacc[df][3] *= resc;
    }

    // ---- pack P -> bf16 pairs; redistribute P^T into PV B-operand; PV MFMAs ----
    unsigned U[4][2];
#pragma unroll
    for (int kf = 0; kf < 4; ++kf) {
      U[kf][0] = pack2(p[kf][0], p[kf][1]);
      U[kf][1] = pack2(p[kf][2], p[kf][3]);
    }
#pragma unroll
    for (int ks = 0; ks < 2; ++ks) {
      unsigned bb[4];
#pragma unroll
      for (int m = 0; m < 4; ++m) {
        const int src = llo + ((((lhi & 1) << 1) + (m >> 1)) << 4);
        const int va = __shfl((int)U[2 * ks + 0][m & 1], src);
        const int vb = __shfl((int)U[2 * ks + 1][m & 1], src);
        bb[m] = (lhi >> 1) ? (unsigned)vb : (unsigned)va;
      }
      union { unsigned u[4]; bf16x8 v; } pb_;
      pb_.u[0] = bb[0]; pb_.u[1] = bb[1]; pb_.u[2] = bb[2]; pb_.u[3] = bb[3];
#pragma unroll
      for (int df = 0; df < 4; ++df) {
        const int dr = df * 16 + llo;
        bf16x8 vf = *(const bf16x8*)(vsh + (((dr << 7) + ((ks * 32 + lhi * 8) << 1)) ^ ((dr & 7) << 4)));
        oacc[df] = __builtin_amdgcn_mfma_f32_16x16x32_bf16(vf, pb_.v, oacc[df], 0, 0, 0);
      }
    }
    barw();   // all waves done reading ksh/vsh before next staging overwrite
  } // kv tiles

  // ---- write partial (unnormalized O, m, l) ----
  float* pb = opart + (size_t)((h * 32 + qt) * 2 + half) * PARTF;
  const int rowl = w * 16 + llo;
#pragma unroll
  for (int df = 0; df < 4; ++df) {
    *(f32x4*)(pb + rowl * 64 + df * 16 + lhi * 4) = oacc[df];
  }
  if (lhi == 0) {
    pb[4096 + rowl] = m_r;
    pb[4160 + rowl] = l_r;
  }
}

// ============================================================================
// combine: merge the two kv-half partials per (qt,h); dead rows -> V col-mean.
// ============================================================================
__global__ __launch_bounds__(256) void attend_combine(
    const float* __restrict__ opart, const float* __restrict__ vg,
    float* __restrict__ outg)
{
  __shared__ float vmean_s[DDIM];
  const int qt = blockIdx.x;
  const int h  = blockIdx.y;
  const int t  = threadIdx.x;
  const float* p0 = opart + (size_t)((h * 32 + qt) * 2 + 0) * PARTF;
  const float* p1 = opart + (size_t)((h * 32 + qt) * 2 + 1) * PARTF;
  const int r  = t >> 2;          // 0..63
  const int c0 = (t & 3) * 16;    // 0,16,32,48

  const float m1 = p0[4096 + r], l1 = p0[4160 + r];
  const float m2 = p1[4096 + r], l2 = p1[4160 + r];
  const float m  = fmaxf(m1, m2);
  const float w1 = __expf(m1 - m);
  const float w2 = __expf(m2 - m);
  const float l  = l1 * w1 + l2 * w2;
  const bool dead = (m == -FLT_MAX);

  const int anyNeed = __syncthreads_or(dead);
  if (anyNeed) {
    if (t < DDIM) vmean_s[t] = 0.f;
    __syncthreads();
    {
      const int d = t & 63, part = t >> 6;
      float sacc = 0.f;
      for (int j = part; j < NN; j += 4) sacc += vg[((size_t)(h * NN + j)) * DDIM + d];
      atomicAdd(&vmean_s[d], sacc);
    }
    __syncthreads();
    if (t < DDIM) vmean_s[t] *= (1.0f / (float)NN);
    __syncthreads();
  }

  const float invl = dead ? 0.f : (1.0f / l);
  float* op = outg + ((size_t)(h * NN) + qt * QB + r) * DDIM + c0;
#pragma unroll
  for (int i = 0; i < 4; ++i) {
    float4 a = *(const float4*)(p0 + r * 64 + c0 + i * 4);
    float4 b = *(const float4*)(p1 + r * 64 + c0 + i * 4);
    float4 o;
    o.x = dead ? vmean_s[c0 + i * 4 + 0] : (a.x * w1 + b.x * w2) * invl;
    o.y = dead ? vmean_s[c0 + i * 4 + 1] : (a.y * w1 + b.y * w2) * invl;
    o.z = dead ? vmean_s[c0 + i * 4 + 2] : (a.z * w1 + b.z * w2) * invl;
    o.w = dead ? vmean_s[c0 + i * 4 + 3] : (a.w * w1 + b.w * w2) * invl;
    *(float4*)(op + i * 4) = o;
  }
}

// ============================================================================
// Fallback: R4 single-kernel version (used only if ws_size is too small).
// ============================================================================
__global__ __launch_bounds__(256, 2) void attend_single(
    const float* __restrict__ qg, const float* __restrict__ kg,
    const float* __restrict__ vg, const unsigned int* __restrict__ maskw,
    const float* __restrict__ biasg, const float* __restrict__ prevg,
    float* __restrict__ outg)
{
  __shared__ char  ksh[KB * 128]   __attribute__((aligned(16)));
  __shared__ char  vsh[DDIM * 128] __attribute__((aligned(16)));
  __shared__ float vmean_s[DDIM];

  const int t    = threadIdx.x;
  const int lane = t & 63;
  const int w    = t >> 6;
  const int x    = blockIdx.x;
  const int h    = blockIdx.y;
  const int qt   = (h < 8) ? x : (31 - x);
  const int qrow0 = qt * QB;

  unsigned int mwrd = maskw[t & 255];
  const int mask4 = __syncthreads_and(mwrd == 0u || mwrd == 1u || mwrd == 0x3F800000u);

  const int llo = lane & 15;
  const int lhi = lane >> 4;
  const int qrow_g = qrow0 + w * 16 + llo;

  bf16x8 aq[2];
  {
    const float* qp = qg + ((size_t)(h * NN + qrow_g)) * DDIM + lhi * 8;
#pragma unroll
    for (int ks = 0; ks < 2; ++ks) {
      float4 f0 = *(const float4*)(qp + ks * 32);
      float4 f1 = *(const float4*)(qp + ks * 32 + 4);
      bf16x8 a;
      a[0] = (__bf16)(f0.x * 0.125f); a[1] = (__bf16)(f0.y * 0.125f);
      a[2] = (__bf16)(f0.z * 0.125f); a[3] = (__bf16)(f0.w * 0.125f);
      a[4] = (__bf16)(f1.x * 0.125f); a[5] = (__bf16)(f1.y * 0.125f);
      a[6] = (__bf16)(f1.z * 0.125f); a[7] = (__bf16)(f1.w * 0.125f);
      aq[ks] = a;
    }
  }

  f32x4 oacc[4];
#pragma unroll
  for (int i = 0; i < 4; ++i) { f32x4 z = {0.f, 0.f, 0.f, 0.f}; oacc[i] = z; }
  float m_r = -FLT_MAX, l_r = 0.f;

  float4 kpre[4], vpre[4];
  float4 ppre[4], bpre[4];
  uint4  mpre[4];

  auto issueKV = [&](int kv0) {
#pragma unroll
    for (int e = 0; e < 4; ++e) {
      const int f4  = t + e * 256;
      const int row = f4 >> 4;
      const int cb  = (f4 & 15) * 4;
      const size_t gofs = ((size_t)(h * NN + kv0 + row)) * DDIM + cb;
      kpre[e] = *(const float4*)(kg + gofs);
      vpre[e] = *(const float4*)(vg + gofs);
    }
  };
  auto issuePB = [&](int kv0) {
#pragma unroll
    for (int kf = 0; kf < 4; ++kf) {
      const int col = kv0 + kf * 16 + lhi * 4;
      const size_t base = ((size_t)(h * NN) + qrow_g) * NN + col;
      ppre[kf] = *(const float4*)(prevg + base);
      bpre[kf] = *(const float4*)(biasg + base);
      const size_t midx = (size_t)qrow_g * NN + col;
      if (mask4) mpre[kf] = *(const uint4*)(maskw + midx);
      else       mpre[kf].x = *(const unsigned int*)((const unsigned char*)maskw + midx);
    }
  };

  const int Tq = qt + 1;
  issueKV(0);
  issuePB(0);

  for (int tt = 0; tt < Tq; ++tt) {
    const int kv0 = tt * KB;
#pragma unroll
    for (int e = 0; e < 4; ++e) {
      const int f4  = t + e * 256;
      const int row = f4 >> 4;
      const int cb  = (f4 & 15) * 4;
      float4 kf = kpre[e];
      bf16x4 kb4;
      kb4[0] = (__bf16)kf.x; kb4[1] = (__bf16)kf.y;
      kb4[2] = (__bf16)kf.z; kb4[3] = (__bf16)kf.w;
      *(bf16x4*)(ksh + (((row << 7) + (cb << 1)) ^ ((row & 7) << 4))) = kb4;
      float4 vf = vpre[e];
      *(__bf16*)(vsh + ((((cb + 0) << 7) + (row << 1)) ^ (((cb + 0) & 7) << 4))) = (__bf16)vf.x;
      *(__bf16*)(vsh + ((((cb + 1) << 7) + (row << 1)) ^ (((cb + 1) & 7) << 4))) = (__bf16)vf.y;
      *(__bf16*)(vsh + ((((cb + 2) << 7) + (row << 1)) ^ (((cb + 2) & 7) << 4))) = (__bf16)vf.z;
      *(__bf16*)(vsh + ((((cb + 3) << 7) + (row << 1)) ^ (((cb + 3) & 7) << 4))) = (__bf16)vf.w;
    }
    float4 pc[4], bc[4]; uint4 mc[4];
#pragma unroll
    for (int kf = 0; kf < 4; ++kf) { pc[kf] = ppre[kf]; bc[kf] = bpre[kf]; mc[kf] = mpre[kf]; }
    if (tt + 1 < Tq) { issueKV(kv0 + KB); issuePB(kv0 + KB); }
    barw();

    f32x4 s[4];
#pragma unroll
    for (int kf = 0; kf < 4; ++kf) { f32x4 z = {0.f, 0.f, 0.f, 0.f}; s[kf] = z; }
#pragma unroll
    for (int ks = 0; ks < 2; ++ks) {
#pragma unroll
      for (int kf = 0; kf < 4; ++kf) {
        const int kvr = kf * 16 + llo;
        bf16x8 ak = *(const bf16x8*)(ksh + (((kvr << 7) + ((ks * 32 + lhi * 8) << 1)) ^ ((kvr & 7) << 4)));
        s[kf] = __builtin_amdgcn_mfma_f32_16x16x32_bf16(ak, aq[ks], s[kf], 0, 0, 0);
      }
    }

    float p[4][4];
    float pmax = -FLT_MAX;
#pragma unroll
    for (int kf = 0; kf < 4; ++kf) {
      float pa[4] = {pc[kf].x, pc[kf].y, pc[kf].z, pc[kf].w};
      float ba[4] = {bc[kf].x, bc[kf].y, bc[kf].z, bc[kf].w};
      unsigned mb[4];
      if (mask4) { mb[0] = mc[kf].x; mb[1] = mc[kf].y; mb[2] = mc[kf].z; mb[3] = mc[kf].w; }
      else {
        mb[0] = mc[kf].x & 0xffu; mb[1] = (mc[kf].x >> 8) & 0xffu;
        mb[2] = (mc[kf].x >> 16) & 0xffu; mb[3] = mc[kf].x >> 24;
      }
#pragma unroll
      for (int r = 0; r < 4; ++r) {
        const int j = kv0 + kf * 16 + lhi * 4 + r;
        float sv = s[kf][r] + pa[r] + ba[r];
        if (j > qrow_g || mb[r] == 0u) sv = -FLT_MAX;
        p[kf][r] = sv;
        pmax = fmaxf(pmax, sv);
      }
    }
    pmax = fmaxf(pmax, __shfl_xor(pmax, 16));
    pmax = fmaxf(pmax, __shfl_xor(pmax, 32));
    const float mnew = fmaxf(m_r, pmax);
    const float resc = __expf(m_r - mnew);
    float psum = 0.f;
#pragma unroll
    for (int kf = 0; kf < 4; ++kf)
#pragma unroll
      for (int r = 0; r < 4; ++r) {
        float e = __expf(p[kf][r] - mnew);
        p[kf][r] = e;
        psum += e;
      }
    psum += __shfl_xor(psum, 16);
    psum += __shfl_xor(psum, 32);
    l_r = l_r * resc + psum;
    m_r = mnew;
#pragma unroll
    for (int df = 0; df < 4; ++df) {
      oacc[df][0] *= resc; oacc[df][1] *= resc;
      oacc[df][2] *= resc; oacc[df][3] *= resc;
    }

    unsigned U[4][2];
#pragma unroll
    for (int kf = 0; kf < 4; ++kf) {
      U[kf][0] = pack2(p[kf][0], p[kf][1]);
      U[kf][1] = pack2(p[kf][2], p[kf][3]);
    }
#pragma unroll
    for (int ks = 0; ks < 2; ++ks) {
      unsigned bb[4];
#pragma unroll
      for (int m = 0; m < 4; ++m) {
        const int src = llo + ((((lhi & 1) << 1) + (m >> 1)) << 4);
        const int va = __shfl((int)U[2 * ks + 0][m & 1], src);
        const int vb = __shfl((int)U[2 * ks + 1][m & 1], src);
        bb[m] = (lhi >> 1) ? (unsigned)vb : (unsigned)va;
      }
      union { unsigned u[4]; bf16x8 v; } pb_;
      pb_.u[0] = bb[0]; pb_.u[1] = bb[1]; pb_.u[2] = bb[2]; pb_.u[3] = bb[3];
#pragma unroll
      for (int df = 0; df < 4; ++df) {
        const int dr = df * 16 + llo;
        bf16x8 vf = *(const bf16x8*)(vsh + (((dr << 7) + ((ks * 32 + lhi * 8) << 1)) ^ ((dr & 7) << 4)));
        oacc[df] = __builtin_amdgcn_mfma_f32_16x16x32_bf16(vf, pb_.v, oacc[df], 0, 0, 0);
      }
    }
    barw();
  }

  const int anyNeed = __syncthreads_or(m_r == -FLT_MAX);
  if (anyNeed) {
    if (t < DDIM) vmean_s[t] = 0.f;
    __syncthreads();
    {
      const int d = t & 63, part = t >> 6;
      float sacc = 0.f;
      for (int j = part; j < NN; j += 4) sacc += vg[((size_t)(h * NN + j)) * DDIM + d];
      atomicAdd(&vmean_s[d], sacc);
    }
    __syncthreads();
    if (t < DDIM) vmean_s[t] *= (1.0f / (float)NN);
    __syncthreads();
  }
  const float invl = 1.0f / l_r;
  const bool dead = (m_r == -FLT_MAX);
#pragma unroll
  for (int df = 0; df < 4; ++df) {
    const int dbase = df * 16 + lhi * 4;
    float4 o;
    o.x = dead ? vmean_s[dbase + 0] : oacc[df][0] * invl;
    o.y = dead ? vmean_s[dbase + 1] : oacc[df][1] * invl;
    o.z = dead ? vmean_s[dbase + 2] : oacc[df][2] * invl;
    o.w = dead ? vmean_s[dbase + 3] : oacc[df][3] * invl;
    *(float4*)(outg + ((size_t)(h * NN) + qrow_g) * DDIM + dbase) = o;
  }
}

extern "C" void kernel_launch(void* const* d_in, const int* in_sizes, int n_in,
                              void* d_out, int out_size, void* d_ws, size_t ws_size,
                              hipStream_t stream) {
  (void)in_sizes; (void)n_in; (void)out_size;
  const float* q    = (const float*)d_in[0];
  const float* k    = (const float*)d_in[1];
  const float* v    = (const float*)d_in[2];
  const unsigned int* mask = (const unsigned int*)d_in[3];
  const float* bias = (const float*)d_in[4];
  const float* prev = (const float*)d_in[5];
  float* out = (float*)d_out;

  if (ws_size >= WS_NEED) {
    float* opart = (float*)d_ws;
    dim3 grid(64, HH);
    attend_part<<<grid, 256, 0, stream>>>(q, k, v, mask, bias, prev, opart);
    dim3 cgrid(32, HH);
    attend_combine<<<cgrid, 256, 0, stream>>>(opart, v, out);
  } else {
    dim3 grid(32, HH);
    attend_single<<<grid, 256, 0, stream>>>(q, k, v, mask, bias, prev, out);
  }
}

// Round 7
// 319.498 us; speedup vs baseline: 1.6358x; 1.6358x over previous
//
#include <hip/hip_runtime.h>
#include <hip/hip_bf16.h>
#include <float.h>

#define NN 2048
#define HH 16
#define DDIM 64
#define QB 64   // q-rows per block = 4 waves x 16 rows
#define KB 64
#define PARTF 4224            // floats per partial: 64x64 O + 64 m + 64 l
#define WS_NEED (1024ull * PARTF * 4ull)

typedef __bf16 bf16x8 __attribute__((ext_vector_type(8)));
typedef __bf16 bf16x4 __attribute__((ext_vector_type(4)));
typedef float f32x4 __attribute__((ext_vector_type(4)));

// Raw barrier: LDS-writes visible; outstanding GLOBAL prefetch loads stay in flight.
__device__ __forceinline__ void barw() {
  __builtin_amdgcn_sched_barrier(0);
  asm volatile("s_waitcnt lgkmcnt(0)" ::: "memory");
  __builtin_amdgcn_s_barrier();
  __builtin_amdgcn_sched_barrier(0);
}

__device__ __forceinline__ unsigned pack2(float a, float b) {
  union { __bf16 h[2]; unsigned u; } x;
  x.h[0] = (__bf16)a; x.h[1] = (__bf16)b;
  return x.u;
}

// ============================================================================
// R7 main: R6 kv-split structure (1024 blocks, each handles half its q-tile's
// kv range; partials to ws) with the ONE fix: __launch_bounds__(256,2) so the
// allocator keeps the ~120-VGPR prefetch set in registers (R3/R5/R6 all died
// to caps below that). HW occupancy then allows 4 blocks/CU (512/120 = 4
// waves/SIMD, LDS 4x16.9KB).
// x: qt = 31-(x>>1) (big first), half = x&1.
// ============================================================================
__global__ __launch_bounds__(256, 2) void attend_part(
    const float* __restrict__ qg, const float* __restrict__ kg,
    const float* __restrict__ vg, const unsigned int* __restrict__ maskw,
    const float* __restrict__ biasg, const float* __restrict__ prevg,
    float* __restrict__ opart)
{
  __shared__ char ksh[KB * 128]   __attribute__((aligned(16))); // [kv][d] bf16, XOR-swizzled
  __shared__ char vsh[DDIM * 128] __attribute__((aligned(16))); // [d][kv] bf16, XOR-swizzled

  const int t    = threadIdx.x;
  const int lane = t & 63;
  const int w    = t >> 6;
  const int x    = blockIdx.x;   // 0..63
  const int h    = blockIdx.y;
  const int qt   = 31 - (x >> 1);
  const int half = x & 1;
  const int T    = qt + 1;
  const int mid  = (T + 1) >> 1;
  const int lo   = half ? mid : 0;
  const int hi   = half ? T : mid;
  const int qrow0 = qt * QB;

  // --- mask element-width detection: 4-byte (int/float bool) vs 1-byte ---
  unsigned int mwrd = maskw[t & 255];
  const int mask4 = __syncthreads_and(mwrd == 0u || mwrd == 1u || mwrd == 0x3F800000u);

  const int llo = lane & 15;
  const int lhi = lane >> 4;
  const int qrow_g = qrow0 + w * 16 + llo;   // this lane's q-row

  // --- Q fragments (B operand), scale 1/8 folded in ---
  bf16x8 aq[2];
  {
    const float* qp = qg + ((size_t)(h * NN + qrow_g)) * DDIM + lhi * 8;
#pragma unroll
    for (int ks = 0; ks < 2; ++ks) {
      float4 f0 = *(const float4*)(qp + ks * 32);
      float4 f1 = *(const float4*)(qp + ks * 32 + 4);
      bf16x8 a;
      a[0] = (__bf16)(f0.x * 0.125f); a[1] = (__bf16)(f0.y * 0.125f);
      a[2] = (__bf16)(f0.z * 0.125f); a[3] = (__bf16)(f0.w * 0.125f);
      a[4] = (__bf16)(f1.x * 0.125f); a[5] = (__bf16)(f1.y * 0.125f);
      a[6] = (__bf16)(f1.z * 0.125f); a[7] = (__bf16)(f1.w * 0.125f);
      aq[ks] = a;
    }
  }

  f32x4 oacc[4];   // O^T frags: oacc[df][r] = O[q=llo-row][d=df*16+lhi*4+r]
#pragma unroll
  for (int i = 0; i < 4; ++i) { f32x4 z = {0.f, 0.f, 0.f, 0.f}; oacc[i] = z; }
  float m_r = -FLT_MAX, l_r = 0.f;

  // ---- prefetch registers ----
  float4 kpre[4], vpre[4];
  float4 ppre[4], bpre[4];
  uint4  mpre[4];

  auto issueKV = [&](int kv0) {
#pragma unroll
    for (int e = 0; e < 4; ++e) {
      const int f4  = t + e * 256;
      const int row = f4 >> 4;
      const int cb  = (f4 & 15) * 4;
      const size_t gofs = ((size_t)(h * NN + kv0 + row)) * DDIM + cb;
      kpre[e] = *(const float4*)(kg + gofs);
      vpre[e] = *(const float4*)(vg + gofs);
    }
  };
  auto issuePB = [&](int kv0) {
#pragma unroll
    for (int kf = 0; kf < 4; ++kf) {
      const int col = kv0 + kf * 16 + lhi * 4;
      const size_t base = ((size_t)(h * NN) + qrow_g) * NN + col;
      ppre[kf] = *(const float4*)(prevg + base);
      bpre[kf] = *(const float4*)(biasg + base);
      const size_t midx = (size_t)qrow_g * NN + col;
      if (mask4) {
        mpre[kf] = *(const uint4*)(maskw + midx);
      } else {
        mpre[kf].x = *(const unsigned int*)((const unsigned char*)maskw + midx);
      }
    }
  };

  if (lo < hi) { issueKV(lo * KB); issuePB(lo * KB); }

  for (int tt = lo; tt < hi; ++tt) {
    const int kv0 = tt * KB;
    // ---- phase 1: stage K (row-major) and V (transposed), f32->bf16, swizzled ----
#pragma unroll
    for (int e = 0; e < 4; ++e) {
      const int f4  = t + e * 256;
      const int row = f4 >> 4;
      const int cb  = (f4 & 15) * 4;
      float4 kf = kpre[e];
      bf16x4 kb4;
      kb4[0] = (__bf16)kf.x; kb4[1] = (__bf16)kf.y;
      kb4[2] = (__bf16)kf.z; kb4[3] = (__bf16)kf.w;
      *(bf16x4*)(ksh + (((row << 7) + (cb << 1)) ^ ((row & 7) << 4))) = kb4;
      float4 vf = vpre[e];
      *(__bf16*)(vsh + ((((cb + 0) << 7) + (row << 1)) ^ (((cb + 0) & 7) << 4))) = (__bf16)vf.x;
      *(__bf16*)(vsh + ((((cb + 1) << 7) + (row << 1)) ^ (((cb + 1) & 7) << 4))) = (__bf16)vf.y;
      *(__bf16*)(vsh + ((((cb + 2) << 7) + (row << 1)) ^ (((cb + 2) & 7) << 4))) = (__bf16)vf.z;
      *(__bf16*)(vsh + ((((cb + 3) << 7) + (row << 1)) ^ (((cb + 3) & 7) << 4))) = (__bf16)vf.w;
    }
    // keep current tile's softmax operands
    float4 pc[4], bc[4]; uint4 mc[4];
#pragma unroll
    for (int kf = 0; kf < 4; ++kf) { pc[kf] = ppre[kf]; bc[kf] = bpre[kf]; mc[kf] = mpre[kf]; }
    // issue next tile's loads (fly across the raw barriers)
    if (tt + 1 < hi) { issueKV(kv0 + KB); issuePB(kv0 + KB); }
    barw();

    // ---- QK^T swapped: S^T[kv][q], each lane: q=llo-row, 16 kv values ----
    f32x4 s[4];
#pragma unroll
    for (int kf = 0; kf < 4; ++kf) { f32x4 z = {0.f, 0.f, 0.f, 0.f}; s[kf] = z; }
#pragma unroll
    for (int ks = 0; ks < 2; ++ks) {
#pragma unroll
      for (int kf = 0; kf < 4; ++kf) {
        const int kvr = kf * 16 + llo;
        bf16x8 ak = *(const bf16x8*)(ksh + (((kvr << 7) + ((ks * 32 + lhi * 8) << 1)) ^ ((kvr & 7) << 4)));
        s[kf] = __builtin_amdgcn_mfma_f32_16x16x32_bf16(ak, aq[ks], s[kf], 0, 0, 0);
      }
    }

    // ---- softmax, fully in-register (row = q = llo; 4 lanes/row via xor16/32) ----
    float p[4][4];
    float pmax = -FLT_MAX;
#pragma unroll
    for (int kf = 0; kf < 4; ++kf) {
      float pa[4] = {pc[kf].x, pc[kf].y, pc[kf].z, pc[kf].w};
      float ba[4] = {bc[kf].x, bc[kf].y, bc[kf].z, bc[kf].w};
      unsigned mb[4];
      if (mask4) { mb[0] = mc[kf].x; mb[1] = mc[kf].y; mb[2] = mc[kf].z; mb[3] = mc[kf].w; }
      else {
        mb[0] = mc[kf].x & 0xffu; mb[1] = (mc[kf].x >> 8) & 0xffu;
        mb[2] = (mc[kf].x >> 16) & 0xffu; mb[3] = mc[kf].x >> 24;
      }
#pragma unroll
      for (int r = 0; r < 4; ++r) {
        const int j = kv0 + kf * 16 + lhi * 4 + r;
        float sv = s[kf][r] + pa[r] + ba[r];
        if (j > qrow_g || mb[r] == 0u) sv = -FLT_MAX;
        p[kf][r] = sv;
        pmax = fmaxf(pmax, sv);
      }
    }
    pmax = fmaxf(pmax, __shfl_xor(pmax, 16));
    pmax = fmaxf(pmax, __shfl_xor(pmax, 32));
    const float mnew = fmaxf(m_r, pmax);
    const float resc = __expf(m_r - mnew);   // exp(0)=1 when both -FLT_MAX (finite)
    float psum = 0.f;
#pragma unroll
    for (int kf = 0; kf < 4; ++kf)
#pragma unroll
      for (int r = 0; r < 4; ++r) {
        float e = __expf(p[kf][r] - mnew);
        p[kf][r] = e;
        psum += e;
      }
    psum += __shfl_xor(psum, 16);
    psum += __shfl_xor(psum, 32);
    l_r = l_r * resc + psum;
    m_r = mnew;
#pragma unroll
    for (int df = 0; df < 4; ++df) {
      oacc[df][0] *= resc; oacc[df][1] *= resc;
      oacc[df][2] *= resc; oacc[df][3] *= resc;
    }

    // ---- pack P -> bf16 pairs; redistribute P^T into PV B-operand; PV MFMAs ----
    unsigned U[4][2];
#pragma unroll
    for (int kf = 0; kf < 4; ++kf) {
      U[kf][0] = pack2(p[kf][0], p[kf][1]);
      U[kf][1] = pack2(p[kf][2], p[kf][3]);
    }
#pragma unroll
    for (int ks = 0; ks < 2; ++ks) {
      unsigned bb[4];
#pragma unroll
      for (int m = 0; m < 4; ++m) {
        const int src = llo + ((((lhi & 1) << 1) + (m >> 1)) << 4);
        const int va = __shfl((int)U[2 * ks + 0][m & 1], src);
        const int vb = __shfl((int)U[2 * ks + 1][m & 1], src);
        bb[m] = (lhi >> 1) ? (unsigned)vb : (unsigned)va;
      }
      union { unsigned u[4]; bf16x8 v; } pb_;
      pb_.u[0] = bb[0]; pb_.u[1] = bb[1]; pb_.u[2] = bb[2]; pb_.u[3] = bb[3];
#pragma unroll
      for (int df = 0; df < 4; ++df) {
        const int dr = df * 16 + llo;
        bf16x8 vf = *(const bf16x8*)(vsh + (((dr << 7) + ((ks * 32 + lhi * 8) << 1)) ^ ((dr & 7) << 4)));
        oacc[df] = __builtin_amdgcn_mfma_f32_16x16x32_bf16(vf, pb_.v, oacc[df], 0, 0, 0);
      }
    }
    barw();   // all waves done reading ksh/vsh before next staging overwrite
  } // kv tiles

  // ---- write partial (unnormalized O, m, l) ----
  float* pb = opart + (size_t)((h * 32 + qt) * 2 + half) * PARTF;
  const int rowl = w * 16 + llo;
#pragma unroll
  for (int df = 0; df < 4; ++df) {
    *(f32x4*)(pb + rowl * 64 + df * 16 + lhi * 4) = oacc[df];
  }
  if (lhi == 0) {
    pb[4096 + rowl] = m_r;
    pb[4160 + rowl] = l_r;
  }
}

// ============================================================================
// combine: merge the two kv-half partials per (qt,h); dead rows -> V col-mean.
// ============================================================================
__global__ __launch_bounds__(256) void attend_combine(
    const float* __restrict__ opart, const float* __restrict__ vg,
    float* __restrict__ outg)
{
  __shared__ float vmean_s[DDIM];
  const int qt = blockIdx.x;
  const int h  = blockIdx.y;
  const int t  = threadIdx.x;
  const float* p0 = opart + (size_t)((h * 32 + qt) * 2 + 0) * PARTF;
  const float* p1 = opart + (size_t)((h * 32 + qt) * 2 + 1) * PARTF;
  const int r  = t >> 2;          // 0..63
  const int c0 = (t & 3) * 16;    // 0,16,32,48

  const float m1 = p0[4096 + r], l1 = p0[4160 + r];
  const float m2 = p1[4096 + r], l2 = p1[4160 + r];
  const float m  = fmaxf(m1, m2);
  const float w1 = __expf(m1 - m);
  const float w2 = __expf(m2 - m);
  const float l  = l1 * w1 + l2 * w2;
  const bool dead = (m == -FLT_MAX);

  const int anyNeed = __syncthreads_or(dead);
  if (anyNeed) {
    if (t < DDIM) vmean_s[t] = 0.f;
    __syncthreads();
    {
      const int d = t & 63, part = t >> 6;
      float sacc = 0.f;
      for (int j = part; j < NN; j += 4) sacc += vg[((size_t)(h * NN + j)) * DDIM + d];
      atomicAdd(&vmean_s[d], sacc);
    }
    __syncthreads();
    if (t < DDIM) vmean_s[t] *= (1.0f / (float)NN);
    __syncthreads();
  }

  const float invl = dead ? 0.f : (1.0f / l);
  float* op = outg + ((size_t)(h * NN) + qt * QB + r) * DDIM + c0;
#pragma unroll
  for (int i = 0; i < 4; ++i) {
    float4 a = *(const float4*)(p0 + r * 64 + c0 + i * 4);
    float4 b = *(const float4*)(p1 + r * 64 + c0 + i * 4);
    float4 o;
    o.x = dead ? vmean_s[c0 + i * 4 + 0] : (a.x * w1 + b.x * w2) * invl;
    o.y = dead ? vmean_s[c0 + i * 4 + 1] : (a.y * w1 + b.y * w2) * invl;
    o.z = dead ? vmean_s[c0 + i * 4 + 2] : (a.z * w1 + b.z * w2) * invl;
    o.w = dead ? vmean_s[c0 + i * 4 + 3] : (a.w * w1 + b.w * w2) * invl;
    *(float4*)(op + i * 4) = o;
  }
}

// ============================================================================
// Fallback: R4 single-kernel version (used only if ws_size is too small).
// ============================================================================
__global__ __launch_bounds__(256, 2) void attend_single(
    const float* __restrict__ qg, const float* __restrict__ kg,
    const float* __restrict__ vg, const unsigned int* __restrict__ maskw,
    const float* __restrict__ biasg, const float* __restrict__ prevg,
    float* __restrict__ outg)
{
  __shared__ char  ksh[KB * 128]   __attribute__((aligned(16)));
  __shared__ char  vsh[DDIM * 128] __attribute__((aligned(16)));
  __shared__ float vmean_s[DDIM];

  const int t    = threadIdx.x;
  const int lane = t & 63;
  const int w    = t >> 6;
  const int x    = blockIdx.x;
  const int h    = blockIdx.y;
  const int qt   = (h < 8) ? x : (31 - x);
  const int qrow0 = qt * QB;

  unsigned int mwrd = maskw[t & 255];
  const int mask4 = __syncthreads_and(mwrd == 0u || mwrd == 1u || mwrd == 0x3F800000u);

  const int llo = lane & 15;
  const int lhi = lane >> 4;
  const int qrow_g = qrow0 + w * 16 + llo;

  bf16x8 aq[2];
  {
    const float* qp = qg + ((size_t)(h * NN + qrow_g)) * DDIM + lhi * 8;
#pragma unroll
    for (int ks = 0; ks < 2; ++ks) {
      float4 f0 = *(const float4*)(qp + ks * 32);
      float4 f1 = *(const float4*)(qp + ks * 32 + 4);
      bf16x8 a;
      a[0] = (__bf16)(f0.x * 0.125f); a[1] = (__bf16)(f0.y * 0.125f);
      a[2] = (__bf16)(f0.z * 0.125f); a[3] = (__bf16)(f0.w * 0.125f);
      a[4] = (__bf16)(f1.x * 0.125f); a[5] = (__bf16)(f1.y * 0.125f);
      a[6] = (__bf16)(f1.z * 0.125f); a[7] = (__bf16)(f1.w * 0.125f);
      aq[ks] = a;
    }
  }

  f32x4 oacc[4];
#pragma unroll
  for (int i = 0; i < 4; ++i) { f32x4 z = {0.f, 0.f, 0.f, 0.f}; oacc[i] = z; }
  float m_r = -FLT_MAX, l_r = 0.f;

  float4 kpre[4], vpre[4];
  float4 ppre[4], bpre[4];
  uint4  mpre[4];

  auto issueKV = [&](int kv0) {
#pragma unroll
    for (int e = 0; e < 4; ++e) {
      const int f4  = t + e * 256;
      const int row = f4 >> 4;
      const int cb  = (f4 & 15) * 4;
      const size_t gofs = ((size_t)(h * NN + kv0 + row)) * DDIM + cb;
      kpre[e] = *(const float4*)(kg + gofs);
      vpre[e] = *(const float4*)(vg + gofs);
    }
  };
  auto issuePB = [&](int kv0) {
#pragma unroll
    for (int kf = 0; kf < 4; ++kf) {
      const int col = kv0 + kf * 16 + lhi * 4;
      const size_t base = ((size_t)(h * NN) + qrow_g) * NN + col;
      ppre[kf] = *(const float4*)(prevg + base);
      bpre[kf] = *(const float4*)(biasg + base);
      const size_t midx = (size_t)qrow_g * NN + col;
      if (mask4) mpre[kf] = *(const uint4*)(maskw + midx);
      else       mpre[kf].x = *(const unsigned int*)((const unsigned char*)maskw + midx);
    }
  };

  const int Tq = qt + 1;
  issueKV(0);
  issuePB(0);

  for (int tt = 0; tt < Tq; ++tt) {
    const int kv0 = tt * KB;
#pragma unroll
    for (int e = 0; e < 4; ++e) {
      const int f4  = t + e * 256;
      const int row = f4 >> 4;
      const int cb  = (f4 & 15) * 4;
      float4 kf = kpre[e];
      bf16x4 kb4;
      kb4[0] = (__bf16)kf.x; kb4[1] = (__bf16)kf.y;
      kb4[2] = (__bf16)kf.z; kb4[3] = (__bf16)kf.w;
      *(bf16x4*)(ksh + (((row << 7) + (cb << 1)) ^ ((row & 7) << 4))) = kb4;
      float4 vf = vpre[e];
      *(__bf16*)(vsh + ((((cb + 0) << 7) + (row << 1)) ^ (((cb + 0) & 7) << 4))) = (__bf16)vf.x;
      *(__bf16*)(vsh + ((((cb + 1) << 7) + (row << 1)) ^ (((cb + 1) & 7) << 4))) = (__bf16)vf.y;
      *(__bf16*)(vsh + ((((cb + 2) << 7) + (row << 1)) ^ (((cb + 2) & 7) << 4))) = (__bf16)vf.z;
      *(__bf16*)(vsh + ((((cb + 3) << 7) + (row << 1)) ^ (((cb + 3) & 7) << 4))) = (__bf16)vf.w;
    }
    float4 pc[4], bc[4]; uint4 mc[4];
#pragma unroll
    for (int kf = 0; kf < 4; ++kf) { pc[kf] = ppre[kf]; bc[kf] = bpre[kf]; mc[kf] = mpre[kf]; }
    if (tt + 1 < Tq) { issueKV(kv0 + KB); issuePB(kv0 + KB); }
    barw();

    f32x4 s[4];
#pragma unroll
    for (int kf = 0; kf < 4; ++kf) { f32x4 z = {0.f, 0.f, 0.f, 0.f}; s[kf] = z; }
#pragma unroll
    for (int ks = 0; ks < 2; ++ks) {
#pragma unroll
      for (int kf = 0; kf < 4; ++kf) {
        const int kvr = kf * 16 + llo;
        bf16x8 ak = *(const bf16x8*)(ksh + (((kvr << 7) + ((ks * 32 + lhi * 8) << 1)) ^ ((kvr & 7) << 4)));
        s[kf] = __builtin_amdgcn_mfma_f32_16x16x32_bf16(ak, aq[ks], s[kf], 0, 0, 0);
      }
    }

    float p[4][4];
    float pmax = -FLT_MAX;
#pragma unroll
    for (int kf = 0; kf < 4; ++kf) {
      float pa[4] = {pc[kf].x, pc[kf].y, pc[kf].z, pc[kf].w};
      float ba[4] = {bc[kf].x, bc[kf].y, bc[kf].z, bc[kf].w};
      unsigned mb[4];
      if (mask4) { mb[0] = mc[kf].x; mb[1] = mc[kf].y; mb[2] = mc[kf].z; mb[3] = mc[kf].w; }
      else {
        mb[0] = mc[kf].x & 0xffu; mb[1] = (mc[kf].x >> 8) & 0xffu;
        mb[2] = (mc[kf].x >> 16) & 0xffu; mb[3] = mc[kf].x >> 24;
      }
#pragma unroll
      for (int r = 0; r < 4; ++r) {
        const int j = kv0 + kf * 16 + lhi * 4 + r;
        float sv = s[kf][r] + pa[r] + ba[r];
        if (j > qrow_g || mb[r] == 0u) sv = -FLT_MAX;
        p[kf][r] = sv;
        pmax = fmaxf(pmax, sv);
      }
    }
    pmax = fmaxf(pmax, __shfl_xor(pmax, 16));
    pmax = fmaxf(pmax, __shfl_xor(pmax, 32));
    const float mnew = fmaxf(m_r, pmax);
    const float resc = __expf(m_r - mnew);
    float psum = 0.f;
#pragma unroll
    for (int kf = 0; kf < 4; ++kf)
#pragma unroll
      for (int r = 0; r < 4; ++r) {
        float e = __expf(p[kf][r] - mnew);
        p[kf][r] = e;
        psum += e;
      }
    psum += __shfl_xor(psum, 16);
    psum += __shfl_xor(psum, 32);
    l_r = l_r * resc + psum;
    m_r = mnew;
#pragma unroll
    for (int df = 0; df < 4; ++df) {
      oacc[df][0] *= resc; oacc[df][1] *= resc;
      oacc[df][2] *= resc; oacc[df][3] *= resc;
    }

    unsigned U[4][2];
#pragma unroll
    for (int kf = 0; kf < 4; ++kf) {
      U[kf][0] = pack2(p[kf][0], p[kf][1]);
      U[kf][1] = pack2(p[kf][2], p[kf][3]);
    }
#pragma unroll
    for (int ks = 0; ks < 2; ++ks) {
      unsigned bb[4];
#pragma unroll
      for (int m = 0; m < 4; ++m) {
        const int src = llo + ((((lhi & 1) << 1) + (m >> 1)) << 4);
        const int va = __shfl((int)U[2 * ks + 0][m & 1], src);
        const int vb = __shfl((int)U[2 * ks + 1][m & 1], src);
        bb[m] = (lhi >> 1) ? (unsigned)vb : (unsigned)va;
      }
      union { unsigned u[4]; bf16x8 v; } pb_;
      pb_.u[0] = bb[0]; pb_.u[1] = bb[1]; pb_.u[2] = bb[2]; pb_.u[3] = bb[3];
#pragma unroll
      for (int df = 0; df < 4; ++df) {
        const int dr = df * 16 + llo;
        bf16x8 vf = *(const bf16x8*)(vsh + (((dr << 7) + ((ks * 32 + lhi * 8) << 1)) ^ ((dr & 7) << 4)));
        oacc[df] = __builtin_amdgcn_mfma_f32_16x16x32_bf16(vf, pb_.v, oacc[df], 0, 0, 0);
      }
    }
    barw();
  }

  const int anyNeed = __syncthreads_or(m_r == -FLT_MAX);
  if (anyNeed) {
    if (t < DDIM) vmean_s[t] = 0.f;
    __syncthreads();
    {
      const int d = t & 63, part = t >> 6;
      float sacc = 0.f;
      for (int j = part; j < NN; j += 4) sacc += vg[((size_t)(h * NN + j)) * DDIM + d];
      atomicAdd(&vmean_s[d], sacc);
    }
    __syncthreads();
    if (t < DDIM) vmean_s[t] *= (1.0f / (float)NN);
    __syncthreads();
  }
  const float invl = 1.0f / l_r;
  const bool dead = (m_r == -FLT_MAX);
#pragma unroll
  for (int df = 0; df < 4; ++df) {
    const int dbase = df * 16 + lhi * 4;
    float4 o;
    o.x = dead ? vmean_s[dbase + 0] : oacc[df][0] * invl;
    o.y = dead ? vmean_s[dbase + 1] : oacc[df][1] * invl;
    o.z = dead ? vmean_s[dbase + 2] : oacc[df][2] * invl;
    o.w = dead ? vmean_s[dbase + 3] : oacc[df][3] * invl;
    *(float4*)(outg + ((size_t)(h * NN) + qrow_g) * DDIM + dbase) = o;
  }
}

extern "C" void kernel_launch(void* const* d_in, const int* in_sizes, int n_in,
                              void* d_out, int out_size, void* d_ws, size_t ws_size,
                              hipStream_t stream) {
  (void)in_sizes; (void)n_in; (void)out_size;
  const float* q    = (const float*)d_in[0];
  const float* k    = (const float*)d_in[1];
  const float* v    = (const float*)d_in[2];
  const unsigned int* mask = (const unsigned int*)d_in[3];
  const float* bias = (const float*)d_in[4];
  const float* prev = (const float*)d_in[5];
  float* out = (float*)d_out;

  if (ws_size >= WS_NEED) {
    float* opart = (float*)d_ws;
    dim3 grid(64, HH);
    attend_part<<<grid, 256, 0, stream>>>(q, k, v, mask, bias, prev, opart);
    dim3 cgrid(32, HH);
    attend_combine<<<cgrid, 256, 0, stream>>>(opart, v, out);
  } else {
    dim3 grid(32, HH);
    attend_single<<<grid, 256, 0, stream>>>(q, k, v, mask, bias, prev, out);
  }
}

// Round 8
// 237.600 us; speedup vs baseline: 2.1997x; 1.3447x over previous
//
#include <hip/hip_runtime.h>
#include <hip/hip_bf16.h>
#include <float.h>

#define NN 2048
#define HH 16
#define DDIM 64
#define QB 64   // q-rows per block = 4 waves x 16 rows
#define KB 64
#define PARTF 4224            // floats per partial: 64x64 O + 64 m + 64 l
#define NSLOT 4               // max chunks (kv partials) per q-tile
#define WS_NEED (32ull * HH * NSLOT * PARTF * 4ull)   // 34.6 MB

typedef __bf16 bf16x8 __attribute__((ext_vector_type(8)));
typedef __bf16 bf16x4 __attribute__((ext_vector_type(4)));
typedef float f32x4 __attribute__((ext_vector_type(4)));

// Raw barrier: LDS-writes visible; outstanding GLOBAL prefetch loads stay in flight.
__device__ __forceinline__ void barw() {
  __builtin_amdgcn_sched_barrier(0);
  asm volatile("s_waitcnt lgkmcnt(0)" ::: "memory");
  __builtin_amdgcn_s_barrier();
  __builtin_amdgcn_sched_barrier(0);
}

__device__ __forceinline__ unsigned pack2(float a, float b) {
  union { __bf16 h[2]; unsigned u; } x;
  x.h[0] = (__bf16)a; x.h[1] = (__bf16)b;
  return x.u;
}

// ============================================================================
// R8: equal-chunk decomposition. Each block = (q-tile qt, kv-chunk of <=8
// tiles). 80 chunks/head, flat id = rank*16 + h with ranks sorted by chunk
// size DESC -> a CU's 4 resident blocks have ranks {k,k+16,k+32,k+48}
// (sizes 8,8,8,5-8) + refill rank k+64 (size<=4): per-CU ~30-36 tile-units
// vs ideal 33 (R7's same-x grid gave the critical CUs 64).
// Rank decode: 0..51 = full chunks (qt desc, ci asc); 52..79 = remainders,
// size s = 7-((k-52)>>2), j=(k-52)&3 -> qt = s+8j-1, start tile 8j.
// ============================================================================
__global__ __launch_bounds__(256, 2) void attend_part(
    const float* __restrict__ qg, const float* __restrict__ kg,
    const float* __restrict__ vg, const unsigned int* __restrict__ maskw,
    const float* __restrict__ biasg, const float* __restrict__ prevg,
    float* __restrict__ opart)
{
  __shared__ char ksh[KB * 128]   __attribute__((aligned(16))); // [kv][d] bf16, XOR-swizzled
  __shared__ char vsh[DDIM * 128] __attribute__((aligned(16))); // [d][kv] bf16, XOR-swizzled

  const int t    = threadIdx.x;
  const int lane = t & 63;
  const int w    = t >> 6;
  const int b    = blockIdx.x;   // 0..1279
  const int rank = b >> 4;
  const int h    = b & 15;

  int qt, c0t, len;
  if (rank < 52) {
    int kk = rank;
    qt = 31;
    for (;;) {
      const int nf = (qt + 1) >> 3;
      if (kk < nf) { c0t = kk << 3; len = 8; break; }
      kk -= nf; --qt;
    }
  } else {
    const int s = 7 - ((rank - 52) >> 2);
    const int j = (rank - 52) & 3;
    qt  = s + (j << 3) - 1;
    c0t = j << 3;
    len = s;
  }
  const int ci = c0t >> 3;
  const int lo = c0t;
  const int hi = c0t + len;
  const int qrow0 = qt * QB;

  // --- mask element-width detection: 4-byte (int/float bool) vs 1-byte ---
  unsigned int mwrd = maskw[t & 255];
  const int mask4 = __syncthreads_and(mwrd == 0u || mwrd == 1u || mwrd == 0x3F800000u);

  const int llo = lane & 15;
  const int lhi = lane >> 4;
  const int qrow_g = qrow0 + w * 16 + llo;   // this lane's q-row

  // --- Q fragments (B operand), scale 1/8 folded in ---
  bf16x8 aq[2];
  {
    const float* qp = qg + ((size_t)(h * NN + qrow_g)) * DDIM + lhi * 8;
#pragma unroll
    for (int ks = 0; ks < 2; ++ks) {
      float4 f0 = *(const float4*)(qp + ks * 32);
      float4 f1 = *(const float4*)(qp + ks * 32 + 4);
      bf16x8 a;
      a[0] = (__bf16)(f0.x * 0.125f); a[1] = (__bf16)(f0.y * 0.125f);
      a[2] = (__bf16)(f0.z * 0.125f); a[3] = (__bf16)(f0.w * 0.125f);
      a[4] = (__bf16)(f1.x * 0.125f); a[5] = (__bf16)(f1.y * 0.125f);
      a[6] = (__bf16)(f1.z * 0.125f); a[7] = (__bf16)(f1.w * 0.125f);
      aq[ks] = a;
    }
  }

  f32x4 oacc[4];   // O^T frags: oacc[df][r] = O[q=llo-row][d=df*16+lhi*4+r]
#pragma unroll
  for (int i = 0; i < 4; ++i) { f32x4 z = {0.f, 0.f, 0.f, 0.f}; oacc[i] = z; }
  float m_r = -FLT_MAX, l_r = 0.f;

  // ---- prefetch registers ----
  float4 kpre[4], vpre[4];
  float4 ppre[4], bpre[4];
  uint4  mpre[4];

  auto issueKV = [&](int kv0) {
#pragma unroll
    for (int e = 0; e < 4; ++e) {
      const int f4  = t + e * 256;
      const int row = f4 >> 4;
      const int cb  = (f4 & 15) * 4;
      const size_t gofs = ((size_t)(h * NN + kv0 + row)) * DDIM + cb;
      kpre[e] = *(const float4*)(kg + gofs);
      vpre[e] = *(const float4*)(vg + gofs);
    }
  };
  auto issuePB = [&](int kv0) {
#pragma unroll
    for (int kf = 0; kf < 4; ++kf) {
      const int col = kv0 + kf * 16 + lhi * 4;
      const size_t base = ((size_t)(h * NN) + qrow_g) * NN + col;
      ppre[kf] = *(const float4*)(prevg + base);
      bpre[kf] = *(const float4*)(biasg + base);
      const size_t midx = (size_t)qrow_g * NN + col;
      if (mask4) {
        mpre[kf] = *(const uint4*)(maskw + midx);
      } else {
        mpre[kf].x = *(const unsigned int*)((const unsigned char*)maskw + midx);
      }
    }
  };

  issueKV(lo * KB);
  issuePB(lo * KB);

  for (int tt = lo; tt < hi; ++tt) {
    const int kv0 = tt * KB;
    // ---- phase 1: stage K (row-major) and V (transposed), f32->bf16, swizzled ----
#pragma unroll
    for (int e = 0; e < 4; ++e) {
      const int f4  = t + e * 256;
      const int row = f4 >> 4;
      const int cb  = (f4 & 15) * 4;
      float4 kf = kpre[e];
      bf16x4 kb4;
      kb4[0] = (__bf16)kf.x; kb4[1] = (__bf16)kf.y;
      kb4[2] = (__bf16)kf.z; kb4[3] = (__bf16)kf.w;
      *(bf16x4*)(ksh + (((row << 7) + (cb << 1)) ^ ((row & 7) << 4))) = kb4;
      float4 vf = vpre[e];
      *(__bf16*)(vsh + ((((cb + 0) << 7) + (row << 1)) ^ (((cb + 0) & 7) << 4))) = (__bf16)vf.x;
      *(__bf16*)(vsh + ((((cb + 1) << 7) + (row << 1)) ^ (((cb + 1) & 7) << 4))) = (__bf16)vf.y;
      *(__bf16*)(vsh + ((((cb + 2) << 7) + (row << 1)) ^ (((cb + 2) & 7) << 4))) = (__bf16)vf.z;
      *(__bf16*)(vsh + ((((cb + 3) << 7) + (row << 1)) ^ (((cb + 3) & 7) << 4))) = (__bf16)vf.w;
    }
    // keep current tile's softmax operands
    float4 pc[4], bc[4]; uint4 mc[4];
#pragma unroll
    for (int kf = 0; kf < 4; ++kf) { pc[kf] = ppre[kf]; bc[kf] = bpre[kf]; mc[kf] = mpre[kf]; }
    // issue next tile's loads (fly across the raw barriers)
    if (tt + 1 < hi) { issueKV(kv0 + KB); issuePB(kv0 + KB); }
    barw();

    // ---- QK^T swapped: S^T[kv][q], each lane: q=llo-row, 16 kv values ----
    f32x4 s[4];
#pragma unroll
    for (int kf = 0; kf < 4; ++kf) { f32x4 z = {0.f, 0.f, 0.f, 0.f}; s[kf] = z; }
#pragma unroll
    for (int ks = 0; ks < 2; ++ks) {
#pragma unroll
      for (int kf = 0; kf < 4; ++kf) {
        const int kvr = kf * 16 + llo;
        bf16x8 ak = *(const bf16x8*)(ksh + (((kvr << 7) + ((ks * 32 + lhi * 8) << 1)) ^ ((kvr & 7) << 4)));
        s[kf] = __builtin_amdgcn_mfma_f32_16x16x32_bf16(ak, aq[ks], s[kf], 0, 0, 0);
      }
    }

    // ---- softmax, fully in-register (row = q = llo; 4 lanes/row via xor16/32) ----
    float p[4][4];
    float pmax = -FLT_MAX;
#pragma unroll
    for (int kf = 0; kf < 4; ++kf) {
      float pa[4] = {pc[kf].x, pc[kf].y, pc[kf].z, pc[kf].w};
      float ba[4] = {bc[kf].x, bc[kf].y, bc[kf].z, bc[kf].w};
      unsigned mb[4];
      if (mask4) { mb[0] = mc[kf].x; mb[1] = mc[kf].y; mb[2] = mc[kf].z; mb[3] = mc[kf].w; }
      else {
        mb[0] = mc[kf].x & 0xffu; mb[1] = (mc[kf].x >> 8) & 0xffu;
        mb[2] = (mc[kf].x >> 16) & 0xffu; mb[3] = mc[kf].x >> 24;
      }
#pragma unroll
      for (int r = 0; r < 4; ++r) {
        const int j = kv0 + kf * 16 + lhi * 4 + r;
        float sv = s[kf][r] + pa[r] + ba[r];
        if (j > qrow_g || mb[r] == 0u) sv = -FLT_MAX;
        p[kf][r] = sv;
        pmax = fmaxf(pmax, sv);
      }
    }
    pmax = fmaxf(pmax, __shfl_xor(pmax, 16));
    pmax = fmaxf(pmax, __shfl_xor(pmax, 32));
    const float mnew = fmaxf(m_r, pmax);
    const float resc = __expf(m_r - mnew);   // exp(0)=1 when both -FLT_MAX (finite)
    float psum = 0.f;
#pragma unroll
    for (int kf = 0; kf < 4; ++kf)
#pragma unroll
      for (int r = 0; r < 4; ++r) {
        float e = __expf(p[kf][r] - mnew);
        p[kf][r] = e;
        psum += e;
      }
    psum += __shfl_xor(psum, 16);
    psum += __shfl_xor(psum, 32);
    l_r = l_r * resc + psum;
    m_r = mnew;
#pragma unroll
    for (int df = 0; df < 4; ++df) {
      oacc[df][0] *= resc; oacc[df][1] *= resc;
      oacc[df][2] *= resc; oacc[df][3] *= resc;
    }

    // ---- pack P -> bf16 pairs; redistribute P^T into PV B-operand; PV MFMAs ----
    unsigned U[4][2];
#pragma unroll
    for (int kf = 0; kf < 4; ++kf) {
      U[kf][0] = pack2(p[kf][0], p[kf][1]);
      U[kf][1] = pack2(p[kf][2], p[kf][3]);
    }
#pragma unroll
    for (int ks = 0; ks < 2; ++ks) {
      unsigned bb[4];
#pragma unroll
      for (int m = 0; m < 4; ++m) {
        const int src = llo + ((((lhi & 1) << 1) + (m >> 1)) << 4);
        const int va = __shfl((int)U[2 * ks + 0][m & 1], src);
        const int vb = __shfl((int)U[2 * ks + 1][m & 1], src);
        bb[m] = (lhi >> 1) ? (unsigned)vb : (unsigned)va;
      }
      union { unsigned u[4]; bf16x8 v; } pb_;
      pb_.u[0] = bb[0]; pb_.u[1] = bb[1]; pb_.u[2] = bb[2]; pb_.u[3] = bb[3];
#pragma unroll
      for (int df = 0; df < 4; ++df) {
        const int dr = df * 16 + llo;
        bf16x8 vf = *(const bf16x8*)(vsh + (((dr << 7) + ((ks * 32 + lhi * 8) << 1)) ^ ((dr & 7) << 4)));
        oacc[df] = __builtin_amdgcn_mfma_f32_16x16x32_bf16(vf, pb_.v, oacc[df], 0, 0, 0);
      }
    }
    barw();   // all waves done reading ksh/vsh before next staging overwrite
  } // kv tiles

  // ---- write partial (unnormalized O, m, l) ----
  float* pb = opart + (size_t)(((h * 32 + qt) << 2) + ci) * PARTF;
  const int rowl = w * 16 + llo;
#pragma unroll
  for (int df = 0; df < 4; ++df) {
    *(f32x4*)(pb + rowl * 64 + df * 16 + lhi * 4) = oacc[df];
  }
  if (lhi == 0) {
    pb[4096 + rowl] = m_r;
    pb[4160 + rowl] = l_r;
  }
}

// ============================================================================
// combine: merge up to 4 kv-chunk partials per (qt,h); dead rows -> V col-mean.
// ============================================================================
__global__ __launch_bounds__(256) void attend_combine(
    const float* __restrict__ opart, const float* __restrict__ vg,
    float* __restrict__ outg)
{
  __shared__ float vmean_s[DDIM];
  const int qt  = blockIdx.x;
  const int h   = blockIdx.y;
  const int t   = threadIdx.x;
  const int nch = (qt + 8) >> 3;   // ceil((qt+1)/8)
  const float* base = opart + (size_t)((h * 32 + qt) << 2) * PARTF;
  const int r  = t >> 2;          // 0..63
  const int c0 = (t & 3) * 16;    // 0,16,32,48

  float ml[NSLOT], ll[NSLOT];
  float m = -FLT_MAX;
  for (int ci = 0; ci < nch; ++ci) {
    ml[ci] = base[(size_t)ci * PARTF + 4096 + r];
    ll[ci] = base[(size_t)ci * PARTF + 4160 + r];
    m = fmaxf(m, ml[ci]);
  }
  const bool dead = (m == -FLT_MAX);
  float wgt[NSLOT];
  float l = 0.f;
  for (int ci = 0; ci < nch; ++ci) {
    wgt[ci] = dead ? 0.f : __expf(ml[ci] - m);
    l += ll[ci] * wgt[ci];
  }

  const int anyNeed = __syncthreads_or(dead);
  if (anyNeed) {
    if (t < DDIM) vmean_s[t] = 0.f;
    __syncthreads();
    {
      const int d = t & 63, part = t >> 6;
      float sacc = 0.f;
      for (int j = part; j < NN; j += 4) sacc += vg[((size_t)(h * NN + j)) * DDIM + d];
      atomicAdd(&vmean_s[d], sacc);
    }
    __syncthreads();
    if (t < DDIM) vmean_s[t] *= (1.0f / (float)NN);
    __syncthreads();
  }

  const float invl = dead ? 0.f : (1.0f / l);
  float* op = outg + ((size_t)(h * NN) + qt * QB + r) * DDIM + c0;
#pragma unroll
  for (int i = 0; i < 4; ++i) {
    float4 acc = {0.f, 0.f, 0.f, 0.f};
    for (int ci = 0; ci < nch; ++ci) {
      float4 a = *(const float4*)(base + (size_t)ci * PARTF + r * 64 + c0 + i * 4);
      acc.x += a.x * wgt[ci]; acc.y += a.y * wgt[ci];
      acc.z += a.z * wgt[ci]; acc.w += a.w * wgt[ci];
    }
    float4 o;
    o.x = dead ? vmean_s[c0 + i * 4 + 0] : acc.x * invl;
    o.y = dead ? vmean_s[c0 + i * 4 + 1] : acc.y * invl;
    o.z = dead ? vmean_s[c0 + i * 4 + 2] : acc.z * invl;
    o.w = dead ? vmean_s[c0 + i * 4 + 3] : acc.w * invl;
    *(float4*)(op + i * 4) = o;
  }
}

// ============================================================================
// Fallback: R4 single-kernel version (used only if ws_size is too small).
// ============================================================================
__global__ __launch_bounds__(256, 2) void attend_single(
    const float* __restrict__ qg, const float* __restrict__ kg,
    const float* __restrict__ vg, const unsigned int* __restrict__ maskw,
    const float* __restrict__ biasg, const float* __restrict__ prevg,
    float* __restrict__ outg)
{
  __shared__ char  ksh[KB * 128]   __attribute__((aligned(16)));
  __shared__ char  vsh[DDIM * 128] __attribute__((aligned(16)));
  __shared__ float vmean_s[DDIM];

  const int t    = threadIdx.x;
  const int lane = t & 63;
  const int w    = t >> 6;
  const int x    = blockIdx.x;
  const int h    = blockIdx.y;
  const int qt   = (h < 8) ? x : (31 - x);
  const int qrow0 = qt * QB;

  unsigned int mwrd = maskw[t & 255];
  const int mask4 = __syncthreads_and(mwrd == 0u || mwrd == 1u || mwrd == 0x3F800000u);

  const int llo = lane & 15;
  const int lhi = lane >> 4;
  const int qrow_g = qrow0 + w * 16 + llo;

  bf16x8 aq[2];
  {
    const float* qp = qg + ((size_t)(h * NN + qrow_g)) * DDIM + lhi * 8;
#pragma unroll
    for (int ks = 0; ks < 2; ++ks) {
      float4 f0 = *(const float4*)(qp + ks * 32);
      float4 f1 = *(const float4*)(qp + ks * 32 + 4);
      bf16x8 a;
      a[0] = (__bf16)(f0.x * 0.125f); a[1] = (__bf16)(f0.y * 0.125f);
      a[2] = (__bf16)(f0.z * 0.125f); a[3] = (__bf16)(f0.w * 0.125f);
      a[4] = (__bf16)(f1.x * 0.125f); a[5] = (__bf16)(f1.y * 0.125f);
      a[6] = (__bf16)(f1.z * 0.125f); a[7] = (__bf16)(f1.w * 0.125f);
      aq[ks] = a;
    }
  }

  f32x4 oacc[4];
#pragma unroll
  for (int i = 0; i < 4; ++i) { f32x4 z = {0.f, 0.f, 0.f, 0.f}; oacc[i] = z; }
  float m_r = -FLT_MAX, l_r = 0.f;

  float4 kpre[4], vpre[4];
  float4 ppre[4], bpre[4];
  uint4  mpre[4];

  auto issueKV = [&](int kv0) {
#pragma unroll
    for (int e = 0; e < 4; ++e) {
      const int f4  = t + e * 256;
      const int row = f4 >> 4;
      const int cb  = (f4 & 15) * 4;
      const size_t gofs = ((size_t)(h * NN + kv0 + row)) * DDIM + cb;
      kpre[e] = *(const float4*)(kg + gofs);
      vpre[e] = *(const float4*)(vg + gofs);
    }
  };
  auto issuePB = [&](int kv0) {
#pragma unroll
    for (int kf = 0; kf < 4; ++kf) {
      const int col = kv0 + kf * 16 + lhi * 4;
      const size_t base = ((size_t)(h * NN) + qrow_g) * NN + col;
      ppre[kf] = *(const float4*)(prevg + base);
      bpre[kf] = *(const float4*)(biasg + base);
      const size_t midx = (size_t)qrow_g * NN + col;
      if (mask4) mpre[kf] = *(const uint4*)(maskw + midx);
      else       mpre[kf].x = *(const unsigned int*)((const unsigned char*)maskw + midx);
    }
  };

  const int Tq = qt + 1;
  issueKV(0);
  issuePB(0);

  for (int tt = 0; tt < Tq; ++tt) {
    const int kv0 = tt * KB;
#pragma unroll
    for (int e = 0; e < 4; ++e) {
      const int f4  = t + e * 256;
      const int row = f4 >> 4;
      const int cb  = (f4 & 15) * 4;
      float4 kf = kpre[e];
      bf16x4 kb4;
      kb4[0] = (__bf16)kf.x; kb4[1] = (__bf16)kf.y;
      kb4[2] = (__bf16)kf.z; kb4[3] = (__bf16)kf.w;
      *(bf16x4*)(ksh + (((row << 7) + (cb << 1)) ^ ((row & 7) << 4))) = kb4;
      float4 vf = vpre[e];
      *(__bf16*)(vsh + ((((cb + 0) << 7) + (row << 1)) ^ (((cb + 0) & 7) << 4))) = (__bf16)vf.x;
      *(__bf16*)(vsh + ((((cb + 1) << 7) + (row << 1)) ^ (((cb + 1) & 7) << 4))) = (__bf16)vf.y;
      *(__bf16*)(vsh + ((((cb + 2) << 7) + (row << 1)) ^ (((cb + 2) & 7) << 4))) = (__bf16)vf.z;
      *(__bf16*)(vsh + ((((cb + 3) << 7) + (row << 1)) ^ (((cb + 3) & 7) << 4))) = (__bf16)vf.w;
    }
    float4 pc[4], bc[4]; uint4 mc[4];
#pragma unroll
    for (int kf = 0; kf < 4; ++kf) { pc[kf] = ppre[kf]; bc[kf] = bpre[kf]; mc[kf] = mpre[kf]; }
    if (tt + 1 < Tq) { issueKV(kv0 + KB); issuePB(kv0 + KB); }
    barw();

    f32x4 s[4];
#pragma unroll
    for (int kf = 0; kf < 4; ++kf) { f32x4 z = {0.f, 0.f, 0.f, 0.f}; s[kf] = z; }
#pragma unroll
    for (int ks = 0; ks < 2; ++ks) {
#pragma unroll
      for (int kf = 0; kf < 4; ++kf) {
        const int kvr = kf * 16 + llo;
        bf16x8 ak = *(const bf16x8*)(ksh + (((kvr << 7) + ((ks * 32 + lhi * 8) << 1)) ^ ((kvr & 7) << 4)));
        s[kf] = __builtin_amdgcn_mfma_f32_16x16x32_bf16(ak, aq[ks], s[kf], 0, 0, 0);
      }
    }

    float p[4][4];
    float pmax = -FLT_MAX;
#pragma unroll
    for (int kf = 0; kf < 4; ++kf) {
      float pa[4] = {pc[kf].x, pc[kf].y, pc[kf].z, pc[kf].w};
      float ba[4] = {bc[kf].x, bc[kf].y, bc[kf].z, bc[kf].w};
      unsigned mb[4];
      if (mask4) { mb[0] = mc[kf].x; mb[1] = mc[kf].y; mb[2] = mc[kf].z; mb[3] = mc[kf].w; }
      else {
        mb[0] = mc[kf].x & 0xffu; mb[1] = (mc[kf].x >> 8) & 0xffu;
        mb[2] = (mc[kf].x >> 16) & 0xffu; mb[3] = mc[kf].x >> 24;
      }
#pragma unroll
      for (int r = 0; r < 4; ++r) {
        const int j = kv0 + kf * 16 + lhi * 4 + r;
        float sv = s[kf][r] + pa[r] + ba[r];
        if (j > qrow_g || mb[r] == 0u) sv = -FLT_MAX;
        p[kf][r] = sv;
        pmax = fmaxf(pmax, sv);
      }
    }
    pmax = fmaxf(pmax, __shfl_xor(pmax, 16));
    pmax = fmaxf(pmax, __shfl_xor(pmax, 32));
    const float mnew = fmaxf(m_r, pmax);
    const float resc = __expf(m_r - mnew);
    float psum = 0.f;
#pragma unroll
    for (int kf = 0; kf < 4; ++kf)
#pragma unroll
      for (int r = 0; r < 4; ++r) {
        float e = __expf(p[kf][r] - mnew);
        p[kf][r] = e;
        psum += e;
      }
    psum += __shfl_xor(psum, 16);
    psum += __shfl_xor(psum, 32);
    l_r = l_r * resc + psum;
    m_r = mnew;
#pragma unroll
    for (int df = 0; df < 4; ++df) {
      oacc[df][0] *= resc; oacc[df][1] *= resc;
      oacc[df][2] *= resc; oacc[df][3] *= resc;
    }

    unsigned U[4][2];
#pragma unroll
    for (int kf = 0; kf < 4; ++kf) {
      U[kf][0] = pack2(p[kf][0], p[kf][1]);
      U[kf][1] = pack2(p[kf][2], p[kf][3]);
    }
#pragma unroll
    for (int ks = 0; ks < 2; ++ks) {
      unsigned bb[4];
#pragma unroll
      for (int m = 0; m < 4; ++m) {
        const int src = llo + ((((lhi & 1) << 1) + (m >> 1)) << 4);
        const int va = __shfl((int)U[2 * ks + 0][m & 1], src);
        const int vb = __shfl((int)U[2 * ks + 1][m & 1], src);
        bb[m] = (lhi >> 1) ? (unsigned)vb : (unsigned)va;
      }
      union { unsigned u[4]; bf16x8 v; } pb_;
      pb_.u[0] = bb[0]; pb_.u[1] = bb[1]; pb_.u[2] = bb[2]; pb_.u[3] = bb[3];
#pragma unroll
      for (int df = 0; df < 4; ++df) {
        const int dr = df * 16 + llo;
        bf16x8 vf = *(const bf16x8*)(vsh + (((dr << 7) + ((ks * 32 + lhi * 8) << 1)) ^ ((dr & 7) << 4)));
        oacc[df] = __builtin_amdgcn_mfma_f32_16x16x32_bf16(vf, pb_.v, oacc[df], 0, 0, 0);
      }
    }
    barw();
  }

  const int anyNeed = __syncthreads_or(m_r == -FLT_MAX);
  if (anyNeed) {
    if (t < DDIM) vmean_s[t] = 0.f;
    __syncthreads();
    {
      const int d = t & 63, part = t >> 6;
      float sacc = 0.f;
      for (int j = part; j < NN; j += 4) sacc += vg[((size_t)(h * NN + j)) * DDIM + d];
      atomicAdd(&vmean_s[d], sacc);
    }
    __syncthreads();
    if (t < DDIM) vmean_s[t] *= (1.0f / (float)NN);
    __syncthreads();
  }
  const float invl = 1.0f / l_r;
  const bool dead = (m_r == -FLT_MAX);
#pragma unroll
  for (int df = 0; df < 4; ++df) {
    const int dbase = df * 16 + lhi * 4;
    float4 o;
    o.x = dead ? vmean_s[dbase + 0] : oacc[df][0] * invl;
    o.y = dead ? vmean_s[dbase + 1] : oacc[df][1] * invl;
    o.z = dead ? vmean_s[dbase + 2] : oacc[df][2] * invl;
    o.w = dead ? vmean_s[dbase + 3] : oacc[df][3] * invl;
    *(float4*)(outg + ((size_t)(h * NN) + qrow_g) * DDIM + dbase) = o;
  }
}

extern "C" void kernel_launch(void* const* d_in, const int* in_sizes, int n_in,
                              void* d_out, int out_size, void* d_ws, size_t ws_size,
                              hipStream_t stream) {
  (void)in_sizes; (void)n_in; (void)out_size;
  const float* q    = (const float*)d_in[0];
  const float* k    = (const float*)d_in[1];
  const float* v    = (const float*)d_in[2];
  const unsigned int* mask = (const unsigned int*)d_in[3];
  const float* bias = (const float*)d_in[4];
  const float* prev = (const float*)d_in[5];
  float* out = (float*)d_out;

  if (ws_size >= WS_NEED) {
    float* opart = (float*)d_ws;
    attend_part<<<dim3(1280), 256, 0, stream>>>(q, k, v, mask, bias, prev, opart);
    attend_combine<<<dim3(32, HH), 256, 0, stream>>>(opart, v, out);
  } else {
    attend_single<<<dim3(32, HH), 256, 0, stream>>>(q, k, v, mask, bias, prev, out);
  }
}

// Round 9
// 158.150 us; speedup vs baseline: 3.3047x; 1.5024x over previous
//
#include <hip/hip_runtime.h>
#include <hip/hip_bf16.h>
#include <float.h>

#define NN 2048
#define HH 16
#define DDIM 64
#define QB 64   // q-rows per block = 4 waves x 16 rows
#define KB 64
#define PARTF 4224            // floats per partial: 64x64 O + 64 m + 64 l
#define NSLOT 8               // max kv-chunk partials per q-tile (32 tiles / 4)
#define NCHUNK 2304           // 16 heads * 144 chunks
#define WS_PART_OFF 2048      // floats offset: [0]=counter, [512..1536) vmean
#define WS_NEED ((WS_PART_OFF + 32ull * HH * NSLOT * PARTF) * 4ull)

typedef __bf16 bf16x8 __attribute__((ext_vector_type(8)));
typedef __bf16 bf16x4 __attribute__((ext_vector_type(4)));
typedef float f32x4 __attribute__((ext_vector_type(4)));

// Raw barrier: LDS-writes visible; outstanding GLOBAL prefetch loads stay in flight.
__device__ __forceinline__ void barw() {
  __builtin_amdgcn_sched_barrier(0);
  asm volatile("s_waitcnt lgkmcnt(0)" ::: "memory");
  __builtin_amdgcn_s_barrier();
  __builtin_amdgcn_sched_barrier(0);
}

__device__ __forceinline__ unsigned pack2(float a, float b) {
  union { __bf16 h[2]; unsigned u; } x;
  x.h[0] = (__bf16)a; x.h[1] = (__bf16)b;
  return x.u;
}

// ============================================================================
// vmean: per-head V column means (for fully-masked rows). 16 blocks, coalesced.
// ============================================================================
__global__ __launch_bounds__(256) void vmean_kernel(
    const float* __restrict__ vg, float* __restrict__ wsv)
{
  __shared__ float red[4][DDIM];
  const int h = blockIdx.x;
  const int t = threadIdx.x;
  const int d = t & 63;
  const int part = t >> 6;        // 0..3, each covers 512 rows
  float s = 0.f;
  const float* vp = vg + ((size_t)(h * NN) + part * 512) * DDIM + d;
  for (int j = 0; j < 512; ++j) s += vp[(size_t)j * DDIM];
  red[part][d] = s;
  __syncthreads();
  if (t < DDIM) {
    wsv[h * DDIM + t] =
      (red[0][t] + red[1][t] + red[2][t] + red[3][t]) * (1.0f / (float)NN);
  }
}

// ============================================================================
// R9 part: persistent work-stealing. 1024 blocks (=4/CU capacity) pull chunks
// (CHUNK=4 kv-tiles) off a global atomic counter -> residency AND balance by
// construction (CP workgroup->CU assignment is undefined; R8's static striping
// assumed round-robin and measured ~1 block/CU effective).
// Chunk c: h = c&15, rank = c>>4 (big-first). rank<120: size-4 chunks, walk
// qt=31 down (nf=(qt+1)>>2). rank>=120: idx=rank-120, s=3-(idx>>3), j=idx&7,
// qt=4j+s-1, lo=4j. Partial slot = (h*32+qt)*8 + ci.
// ============================================================================
__global__ __launch_bounds__(256, 2) void attend_part(
    const float* __restrict__ qg, const float* __restrict__ kg,
    const float* __restrict__ vg, const unsigned int* __restrict__ maskw,
    const float* __restrict__ biasg, const float* __restrict__ prevg,
    float* __restrict__ opart, unsigned int* __restrict__ counter)
{
  __shared__ char ksh[KB * 128]   __attribute__((aligned(16))); // [kv][d] bf16, XOR-swizzled
  __shared__ char vsh[DDIM * 128] __attribute__((aligned(16))); // [d][kv] bf16, XOR-swizzled
  __shared__ int chunk_s;

  const int t    = threadIdx.x;
  const int lane = t & 63;
  const int w    = t >> 6;

  // --- mask element-width detection: 4-byte (int/float bool) vs 1-byte ---
  unsigned int mwrd = maskw[t & 255];
  const int mask4 = __syncthreads_and(mwrd == 0u || mwrd == 1u || mwrd == 0x3F800000u);

  const int llo = lane & 15;
  const int lhi = lane >> 4;

  for (;;) {
    if (t == 0) chunk_s = (int)atomicAdd(counter, 1u);
    __syncthreads();
    const int c = chunk_s;
    if (c >= NCHUNK) break;
    const int h    = c & 15;
    const int rank = c >> 4;

    int qt, ci, len;
    if (rank < 120) {
      int kk = rank;
      qt = 31;
      for (;;) {
        const int nf = (qt + 1) >> 2;
        if (kk < nf) { ci = kk; len = 4; break; }
        kk -= nf; --qt;
      }
    } else {
      const int idx = rank - 120;
      const int s = 3 - (idx >> 3);
      const int j = idx & 7;
      qt  = (j << 2) + s - 1;
      ci  = j;
      len = s;
    }
    const int lo = ci << 2;
    const int hi = lo + len;
    const int qrow0 = qt * QB;
    const int qrow_g = qrow0 + w * 16 + llo;   // this lane's q-row

    // --- Q fragments (B operand), scale 1/8 folded in ---
    bf16x8 aq[2];
    {
      const float* qp = qg + ((size_t)(h * NN + qrow_g)) * DDIM + lhi * 8;
#pragma unroll
      for (int ks = 0; ks < 2; ++ks) {
        float4 f0 = *(const float4*)(qp + ks * 32);
        float4 f1 = *(const float4*)(qp + ks * 32 + 4);
        bf16x8 a;
        a[0] = (__bf16)(f0.x * 0.125f); a[1] = (__bf16)(f0.y * 0.125f);
        a[2] = (__bf16)(f0.z * 0.125f); a[3] = (__bf16)(f0.w * 0.125f);
        a[4] = (__bf16)(f1.x * 0.125f); a[5] = (__bf16)(f1.y * 0.125f);
        a[6] = (__bf16)(f1.z * 0.125f); a[7] = (__bf16)(f1.w * 0.125f);
        aq[ks] = a;
      }
    }

    f32x4 oacc[4];   // O^T frags: oacc[df][r] = O[q=llo-row][d=df*16+lhi*4+r]
#pragma unroll
    for (int i = 0; i < 4; ++i) { f32x4 z = {0.f, 0.f, 0.f, 0.f}; oacc[i] = z; }
    float m_r = -FLT_MAX, l_r = 0.f;

    // ---- prefetch registers ----
    float4 kpre[4], vpre[4];
    float4 ppre[4], bpre[4];
    uint4  mpre[4];

    auto issueKV = [&](int kv0) {
#pragma unroll
      for (int e = 0; e < 4; ++e) {
        const int f4  = t + e * 256;
        const int row = f4 >> 4;
        const int cb  = (f4 & 15) * 4;
        const size_t gofs = ((size_t)(h * NN + kv0 + row)) * DDIM + cb;
        kpre[e] = *(const float4*)(kg + gofs);
        vpre[e] = *(const float4*)(vg + gofs);
      }
    };
    auto issuePB = [&](int kv0) {
#pragma unroll
      for (int kf = 0; kf < 4; ++kf) {
        const int col = kv0 + kf * 16 + lhi * 4;
        const size_t base = ((size_t)(h * NN) + qrow_g) * NN + col;
        ppre[kf] = *(const float4*)(prevg + base);
        bpre[kf] = *(const float4*)(biasg + base);
        const size_t midx = (size_t)qrow_g * NN + col;
        if (mask4) {
          mpre[kf] = *(const uint4*)(maskw + midx);
        } else {
          mpre[kf].x = *(const unsigned int*)((const unsigned char*)maskw + midx);
        }
      }
    };

    issueKV(lo * KB);
    issuePB(lo * KB);

    for (int tt = lo; tt < hi; ++tt) {
      const int kv0 = tt * KB;
      // ---- phase 1: stage K (row-major) and V (transposed), f32->bf16, swizzled ----
#pragma unroll
      for (int e = 0; e < 4; ++e) {
        const int f4  = t + e * 256;
        const int row = f4 >> 4;
        const int cb  = (f4 & 15) * 4;
        float4 kf = kpre[e];
        bf16x4 kb4;
        kb4[0] = (__bf16)kf.x; kb4[1] = (__bf16)kf.y;
        kb4[2] = (__bf16)kf.z; kb4[3] = (__bf16)kf.w;
        *(bf16x4*)(ksh + (((row << 7) + (cb << 1)) ^ ((row & 7) << 4))) = kb4;
        float4 vf = vpre[e];
        *(__bf16*)(vsh + ((((cb + 0) << 7) + (row << 1)) ^ (((cb + 0) & 7) << 4))) = (__bf16)vf.x;
        *(__bf16*)(vsh + ((((cb + 1) << 7) + (row << 1)) ^ (((cb + 1) & 7) << 4))) = (__bf16)vf.y;
        *(__bf16*)(vsh + ((((cb + 2) << 7) + (row << 1)) ^ (((cb + 2) & 7) << 4))) = (__bf16)vf.z;
        *(__bf16*)(vsh + ((((cb + 3) << 7) + (row << 1)) ^ (((cb + 3) & 7) << 4))) = (__bf16)vf.w;
      }
      // keep current tile's softmax operands
      float4 pc[4], bc[4]; uint4 mc[4];
#pragma unroll
      for (int kf = 0; kf < 4; ++kf) { pc[kf] = ppre[kf]; bc[kf] = bpre[kf]; mc[kf] = mpre[kf]; }
      // issue next tile's loads (fly across the raw barriers)
      if (tt + 1 < hi) { issueKV(kv0 + KB); issuePB(kv0 + KB); }
      barw();

      // ---- QK^T swapped: S^T[kv][q], each lane: q=llo-row, 16 kv values ----
      f32x4 s[4];
#pragma unroll
      for (int kf = 0; kf < 4; ++kf) { f32x4 z = {0.f, 0.f, 0.f, 0.f}; s[kf] = z; }
#pragma unroll
      for (int ks = 0; ks < 2; ++ks) {
#pragma unroll
        for (int kf = 0; kf < 4; ++kf) {
          const int kvr = kf * 16 + llo;
          bf16x8 ak = *(const bf16x8*)(ksh + (((kvr << 7) + ((ks * 32 + lhi * 8) << 1)) ^ ((kvr & 7) << 4)));
          s[kf] = __builtin_amdgcn_mfma_f32_16x16x32_bf16(ak, aq[ks], s[kf], 0, 0, 0);
        }
      }

      // ---- softmax, fully in-register (row = q = llo; 4 lanes/row via xor16/32) ----
      float p[4][4];
      float pmax = -FLT_MAX;
#pragma unroll
      for (int kf = 0; kf < 4; ++kf) {
        float pa[4] = {pc[kf].x, pc[kf].y, pc[kf].z, pc[kf].w};
        float ba[4] = {bc[kf].x, bc[kf].y, bc[kf].z, bc[kf].w};
        unsigned mb[4];
        if (mask4) { mb[0] = mc[kf].x; mb[1] = mc[kf].y; mb[2] = mc[kf].z; mb[3] = mc[kf].w; }
        else {
          mb[0] = mc[kf].x & 0xffu; mb[1] = (mc[kf].x >> 8) & 0xffu;
          mb[2] = (mc[kf].x >> 16) & 0xffu; mb[3] = mc[kf].x >> 24;
        }
#pragma unroll
        for (int r = 0; r < 4; ++r) {
          const int j = kv0 + kf * 16 + lhi * 4 + r;
          float sv = s[kf][r] + pa[r] + ba[r];
          if (j > qrow_g || mb[r] == 0u) sv = -FLT_MAX;
          p[kf][r] = sv;
          pmax = fmaxf(pmax, sv);
        }
      }
      pmax = fmaxf(pmax, __shfl_xor(pmax, 16));
      pmax = fmaxf(pmax, __shfl_xor(pmax, 32));
      const float mnew = fmaxf(m_r, pmax);
      const float resc = __expf(m_r - mnew);   // exp(0)=1 when both -FLT_MAX (finite)
      float psum = 0.f;
#pragma unroll
      for (int kf = 0; kf < 4; ++kf)
#pragma unroll
        for (int r = 0; r < 4; ++r) {
          float e = __expf(p[kf][r] - mnew);
          p[kf][r] = e;
          psum += e;
        }
      psum += __shfl_xor(psum, 16);
      psum += __shfl_xor(psum, 32);
      l_r = l_r * resc + psum;
      m_r = mnew;
#pragma unroll
      for (int df = 0; df < 4; ++df) {
        oacc[df][0] *= resc; oacc[df][1] *= resc;
        oacc[df][2] *= resc; oacc[df][3] *= resc;
      }

      // ---- pack P -> bf16 pairs; redistribute P^T into PV B-operand; PV MFMAs ----
      unsigned U[4][2];
#pragma unroll
      for (int kf = 0; kf < 4; ++kf) {
        U[kf][0] = pack2(p[kf][0], p[kf][1]);
        U[kf][1] = pack2(p[kf][2], p[kf][3]);
      }
#pragma unroll
      for (int ks = 0; ks < 2; ++ks) {
        unsigned bb[4];
#pragma unroll
        for (int m = 0; m < 4; ++m) {
          const int src = llo + ((((lhi & 1) << 1) + (m >> 1)) << 4);
          const int va = __shfl((int)U[2 * ks + 0][m & 1], src);
          const int vb = __shfl((int)U[2 * ks + 1][m & 1], src);
          bb[m] = (lhi >> 1) ? (unsigned)vb : (unsigned)va;
        }
        union { unsigned u[4]; bf16x8 v; } pb_;
        pb_.u[0] = bb[0]; pb_.u[1] = bb[1]; pb_.u[2] = bb[2]; pb_.u[3] = bb[3];
#pragma unroll
        for (int df = 0; df < 4; ++df) {
          const int dr = df * 16 + llo;
          bf16x8 vf = *(const bf16x8*)(vsh + (((dr << 7) + ((ks * 32 + lhi * 8) << 1)) ^ ((dr & 7) << 4)));
          oacc[df] = __builtin_amdgcn_mfma_f32_16x16x32_bf16(vf, pb_.v, oacc[df], 0, 0, 0);
        }
      }
      barw();   // all waves done reading ksh/vsh before next staging overwrite
    } // kv tiles

    // ---- write partial (unnormalized O, m, l) ----
    float* pb = opart + (size_t)(((h * 32 + qt) << 3) + ci) * PARTF;
    const int rowl = w * 16 + llo;
#pragma unroll
    for (int df = 0; df < 4; ++df) {
      *(f32x4*)(pb + rowl * 64 + df * 16 + lhi * 4) = oacc[df];
    }
    if (lhi == 0) {
      pb[4096 + rowl] = m_r;
      pb[4160 + rowl] = l_r;
    }
    __syncthreads();   // chunk done (stores issued); safe to reuse chunk_s/LDS
  } // chunk loop
}

// ============================================================================
// combine: merge up to 8 kv-chunk partials per (qt,h); dead rows -> vmean.
// No runtime-indexed register arrays (rule #20): two passes over partials.
// ============================================================================
__global__ __launch_bounds__(256) void attend_combine(
    const float* __restrict__ opart, const float* __restrict__ wsv,
    float* __restrict__ outg)
{
  const int qt  = blockIdx.x;
  const int h   = blockIdx.y;
  const int t   = threadIdx.x;
  const int nch = (qt + 4) >> 2;   // ceil((qt+1)/4)
  const float* base = opart + (size_t)((h * 32 + qt) << 3) * PARTF;
  const int r  = t >> 2;          // 0..63
  const int c0 = (t & 3) * 16;    // 0,16,32,48

  float m = -FLT_MAX;
  for (int ci = 0; ci < nch; ++ci)
    m = fmaxf(m, base[(size_t)ci * PARTF + 4096 + r]);
  const bool dead = (m == -FLT_MAX);

  float l = 0.f;
  f32x4 a0 = {0,0,0,0}, a1 = {0,0,0,0}, a2 = {0,0,0,0}, a3 = {0,0,0,0};
  for (int ci = 0; ci < nch; ++ci) {
    const float* pb = base + (size_t)ci * PARTF;
    const float wgt = dead ? 0.f : __expf(pb[4096 + r] - m);
    l += pb[4160 + r] * wgt;
    const f32x4 b0 = *(const f32x4*)(pb + r * 64 + c0 + 0);
    const f32x4 b1 = *(const f32x4*)(pb + r * 64 + c0 + 4);
    const f32x4 b2 = *(const f32x4*)(pb + r * 64 + c0 + 8);
    const f32x4 b3 = *(const f32x4*)(pb + r * 64 + c0 + 12);
    a0 += b0 * wgt; a1 += b1 * wgt; a2 += b2 * wgt; a3 += b3 * wgt;
  }

  const float invl = dead ? 0.f : (1.0f / l);
  float* op = outg + ((size_t)(h * NN) + qt * QB + r) * DDIM + c0;
  const float* vm = wsv + h * DDIM + c0;
#pragma unroll
  for (int i = 0; i < 4; ++i) {
    const f32x4 ai = (i == 0) ? a0 : (i == 1) ? a1 : (i == 2) ? a2 : a3;
    float4 o;
    o.x = dead ? vm[i * 4 + 0] : ai[0] * invl;
    o.y = dead ? vm[i * 4 + 1] : ai[1] * invl;
    o.z = dead ? vm[i * 4 + 2] : ai[2] * invl;
    o.w = dead ? vm[i * 4 + 3] : ai[3] * invl;
    *(float4*)(op + i * 4) = o;
  }
}

// ============================================================================
// Fallback: R4 single-kernel version (used only if ws_size is too small).
// ============================================================================
__global__ __launch_bounds__(256, 2) void attend_single(
    const float* __restrict__ qg, const float* __restrict__ kg,
    const float* __restrict__ vg, const unsigned int* __restrict__ maskw,
    const float* __restrict__ biasg, const float* __restrict__ prevg,
    float* __restrict__ outg)
{
  __shared__ char  ksh[KB * 128]   __attribute__((aligned(16)));
  __shared__ char  vsh[DDIM * 128] __attribute__((aligned(16)));
  __shared__ float vmean_s[DDIM];

  const int t    = threadIdx.x;
  const int lane = t & 63;
  const int w    = t >> 6;
  const int x    = blockIdx.x;
  const int h    = blockIdx.y;
  const int qt   = (h < 8) ? x : (31 - x);
  const int qrow0 = qt * QB;

  unsigned int mwrd = maskw[t & 255];
  const int mask4 = __syncthreads_and(mwrd == 0u || mwrd == 1u || mwrd == 0x3F800000u);

  const int llo = lane & 15;
  const int lhi = lane >> 4;
  const int qrow_g = qrow0 + w * 16 + llo;

  bf16x8 aq[2];
  {
    const float* qp = qg + ((size_t)(h * NN + qrow_g)) * DDIM + lhi * 8;
#pragma unroll
    for (int ks = 0; ks < 2; ++ks) {
      float4 f0 = *(const float4*)(qp + ks * 32);
      float4 f1 = *(const float4*)(qp + ks * 32 + 4);
      bf16x8 a;
      a[0] = (__bf16)(f0.x * 0.125f); a[1] = (__bf16)(f0.y * 0.125f);
      a[2] = (__bf16)(f0.z * 0.125f); a[3] = (__bf16)(f0.w * 0.125f);
      a[4] = (__bf16)(f1.x * 0.125f); a[5] = (__bf16)(f1.y * 0.125f);
      a[6] = (__bf16)(f1.z * 0.125f); a[7] = (__bf16)(f1.w * 0.125f);
      aq[ks] = a;
    }
  }

  f32x4 oacc[4];
#pragma unroll
  for (int i = 0; i < 4; ++i) { f32x4 z = {0.f, 0.f, 0.f, 0.f}; oacc[i] = z; }
  float m_r = -FLT_MAX, l_r = 0.f;

  float4 kpre[4], vpre[4];
  float4 ppre[4], bpre[4];
  uint4  mpre[4];

  auto issueKV = [&](int kv0) {
#pragma unroll
    for (int e = 0; e < 4; ++e) {
      const int f4  = t + e * 256;
      const int row = f4 >> 4;
      const int cb  = (f4 & 15) * 4;
      const size_t gofs = ((size_t)(h * NN + kv0 + row)) * DDIM + cb;
      kpre[e] = *(const float4*)(kg + gofs);
      vpre[e] = *(const float4*)(vg + gofs);
    }
  };
  auto issuePB = [&](int kv0) {
#pragma unroll
    for (int kf = 0; kf < 4; ++kf) {
      const int col = kv0 + kf * 16 + lhi * 4;
      const size_t base = ((size_t)(h * NN) + qrow_g) * NN + col;
      ppre[kf] = *(const float4*)(prevg + base);
      bpre[kf] = *(const float4*)(biasg + base);
      const size_t midx = (size_t)qrow_g * NN + col;
      if (mask4) mpre[kf] = *(const uint4*)(maskw + midx);
      else       mpre[kf].x = *(const unsigned int*)((const unsigned char*)maskw + midx);
    }
  };

  const int Tq = qt + 1;
  issueKV(0);
  issuePB(0);

  for (int tt = 0; tt < Tq; ++tt) {
    const int kv0 = tt * KB;
#pragma unroll
    for (int e = 0; e < 4; ++e) {
      const int f4  = t + e * 256;
      const int row = f4 >> 4;
      const int cb  = (f4 & 15) * 4;
      float4 kf = kpre[e];
      bf16x4 kb4;
      kb4[0] = (__bf16)kf.x; kb4[1] = (__bf16)kf.y;
      kb4[2] = (__bf16)kf.z; kb4[3] = (__bf16)kf.w;
      *(bf16x4*)(ksh + (((row << 7) + (cb << 1)) ^ ((row & 7) << 4))) = kb4;
      float4 vf = vpre[e];
      *(__bf16*)(vsh + ((((cb + 0) << 7) + (row << 1)) ^ (((cb + 0) & 7) << 4))) = (__bf16)vf.x;
      *(__bf16*)(vsh + ((((cb + 1) << 7) + (row << 1)) ^ (((cb + 1) & 7) << 4))) = (__bf16)vf.y;
      *(__bf16*)(vsh + ((((cb + 2) << 7) + (row << 1)) ^ (((cb + 2) & 7) << 4))) = (__bf16)vf.z;
      *(__bf16*)(vsh + ((((cb + 3) << 7) + (row << 1)) ^ (((cb + 3) & 7) << 4))) = (__bf16)vf.w;
    }
    float4 pc[4], bc[4]; uint4 mc[4];
#pragma unroll
    for (int kf = 0; kf < 4; ++kf) { pc[kf] = ppre[kf]; bc[kf] = bpre[kf]; mc[kf] = mpre[kf]; }
    if (tt + 1 < Tq) { issueKV(kv0 + KB); issuePB(kv0 + KB); }
    barw();

    f32x4 s[4];
#pragma unroll
    for (int kf = 0; kf < 4; ++kf) { f32x4 z = {0.f, 0.f, 0.f, 0.f}; s[kf] = z; }
#pragma unroll
    for (int ks = 0; ks < 2; ++ks) {
#pragma unroll
      for (int kf = 0; kf < 4; ++kf) {
        const int kvr = kf * 16 + llo;
        bf16x8 ak = *(const bf16x8*)(ksh + (((kvr << 7) + ((ks * 32 + lhi * 8) << 1)) ^ ((kvr & 7) << 4)));
        s[kf] = __builtin_amdgcn_mfma_f32_16x16x32_bf16(ak, aq[ks], s[kf], 0, 0, 0);
      }
    }

    float p[4][4];
    float pmax = -FLT_MAX;
#pragma unroll
    for (int kf = 0; kf < 4; ++kf) {
      float pa[4] = {pc[kf].x, pc[kf].y, pc[kf].z, pc[kf].w};
      float ba[4] = {bc[kf].x, bc[kf].y, bc[kf].z, bc[kf].w};
      unsigned mb[4];
      if (mask4) { mb[0] = mc[kf].x; mb[1] = mc[kf].y; mb[2] = mc[kf].z; mb[3] = mc[kf].w; }
      else {
        mb[0] = mc[kf].x & 0xffu; mb[1] = (mc[kf].x >> 8) & 0xffu;
        mb[2] = (mc[kf].x >> 16) & 0xffu; mb[3] = mc[kf].x >> 24;
      }
#pragma unroll
      for (int r = 0; r < 4; ++r) {
        const int j = kv0 + kf * 16 + lhi * 4 + r;
        float sv = s[kf][r] + pa[r] + ba[r];
        if (j > qrow_g || mb[r] == 0u) sv = -FLT_MAX;
        p[kf][r] = sv;
        pmax = fmaxf(pmax, sv);
      }
    }
    pmax = fmaxf(pmax, __shfl_xor(pmax, 16));
    pmax = fmaxf(pmax, __shfl_xor(pmax, 32));
    const float mnew = fmaxf(m_r, pmax);
    const float resc = __expf(m_r - mnew);
    float psum = 0.f;
#pragma unroll
    for (int kf = 0; kf < 4; ++kf)
#pragma unroll
      for (int r = 0; r < 4; ++r) {
        float e = __expf(p[kf][r] - mnew);
        p[kf][r] = e;
        psum += e;
      }
    psum += __shfl_xor(psum, 16);
    psum += __shfl_xor(psum, 32);
    l_r = l_r * resc + psum;
    m_r = mnew;
#pragma unroll
    for (int df = 0; df < 4; ++df) {
      oacc[df][0] *= resc; oacc[df][1] *= resc;
      oacc[df][2] *= resc; oacc[df][3] *= resc;
    }

    unsigned U[4][2];
#pragma unroll
    for (int kf = 0; kf < 4; ++kf) {
      U[kf][0] = pack2(p[kf][0], p[kf][1]);
      U[kf][1] = pack2(p[kf][2], p[kf][3]);
    }
#pragma unroll
    for (int ks = 0; ks < 2; ++ks) {
      unsigned bb[4];
#pragma unroll
      for (int m = 0; m < 4; ++m) {
        const int src = llo + ((((lhi & 1) << 1) + (m >> 1)) << 4);
        const int va = __shfl((int)U[2 * ks + 0][m & 1], src);
        const int vb = __shfl((int)U[2 * ks + 1][m & 1], src);
        bb[m] = (lhi >> 1) ? (unsigned)vb : (unsigned)va;
      }
      union { unsigned u[4]; bf16x8 v; } pb_;
      pb_.u[0] = bb[0]; pb_.u[1] = bb[1]; pb_.u[2] = bb[2]; pb_.u[3] = bb[3];
#pragma unroll
      for (int df = 0; df < 4; ++df) {
        const int dr = df * 16 + llo;
        bf16x8 vf = *(const bf16x8*)(vsh + (((dr << 7) + ((ks * 32 + lhi * 8) << 1)) ^ ((dr & 7) << 4)));
        oacc[df] = __builtin_amdgcn_mfma_f32_16x16x32_bf16(vf, pb_.v, oacc[df], 0, 0, 0);
      }
    }
    barw();
  }

  const int anyNeed = __syncthreads_or(m_r == -FLT_MAX);
  if (anyNeed) {
    if (t < DDIM) vmean_s[t] = 0.f;
    __syncthreads();
    {
      const int d = t & 63, part = t >> 6;
      float sacc = 0.f;
      for (int j = part; j < NN; j += 4) sacc += vg[((size_t)(h * NN + j)) * DDIM + d];
      atomicAdd(&vmean_s[d], sacc);
    }
    __syncthreads();
    if (t < DDIM) vmean_s[t] *= (1.0f / (float)NN);
    __syncthreads();
  }
  const float invl = 1.0f / l_r;
  const bool dead = (m_r == -FLT_MAX);
#pragma unroll
  for (int df = 0; df < 4; ++df) {
    const int dbase = df * 16 + lhi * 4;
    float4 o;
    o.x = dead ? vmean_s[dbase + 0] : oacc[df][0] * invl;
    o.y = dead ? vmean_s[dbase + 1] : oacc[df][1] * invl;
    o.z = dead ? vmean_s[dbase + 2] : oacc[df][2] * invl;
    o.w = dead ? vmean_s[dbase + 3] : oacc[df][3] * invl;
    *(float4*)(outg + ((size_t)(h * NN) + qrow_g) * DDIM + dbase) = o;
  }
}

extern "C" void kernel_launch(void* const* d_in, const int* in_sizes, int n_in,
                              void* d_out, int out_size, void* d_ws, size_t ws_size,
                              hipStream_t stream) {
  (void)in_sizes; (void)n_in; (void)out_size;
  const float* q    = (const float*)d_in[0];
  const float* k    = (const float*)d_in[1];
  const float* v    = (const float*)d_in[2];
  const unsigned int* mask = (const unsigned int*)d_in[3];
  const float* bias = (const float*)d_in[4];
  const float* prev = (const float*)d_in[5];
  float* out = (float*)d_out;

  if (ws_size >= WS_NEED) {
    float* wsf = (float*)d_ws;
    unsigned int* counter = (unsigned int*)wsf;          // [0]
    float* wsv   = wsf + 512;                            // vmean: 16*64 floats
    float* opart = wsf + WS_PART_OFF;                    // partials
    hipMemsetAsync(counter, 0, 4, stream);
    vmean_kernel<<<dim3(HH), 256, 0, stream>>>(v, wsv);
    attend_part<<<dim3(1024), 256, 0, stream>>>(q, k, v, mask, bias, prev, opart, counter);
    attend_combine<<<dim3(32, HH), 256, 0, stream>>>(opart, wsv, out);
  } else {
    attend_single<<<dim3(32, HH), 256, 0, stream>>>(q, k, v, mask, bias, prev, out);
  }
}

// Round 10
// 155.444 us; speedup vs baseline: 3.3622x; 1.0174x over previous
//
#include <hip/hip_runtime.h>
#include <hip/hip_bf16.h>
#include <float.h>

#define NN 2048
#define HH 16
#define DDIM 64
#define QB 64   // q-rows per block = 4 waves x 16 rows
#define KB 64
#define KPITCH 144            // LDS row pitch in bytes (16B-aligned, bank-spread)
#define PARTF 4224            // floats per partial: 64x64 O + 64 m + 64 l
#define NSLOT 8               // max kv-chunk partials per q-tile (32 tiles / 4)
#define NCHUNK 2304           // 16 heads * 144 chunks
#define WS_PART_OFF 2048      // floats offset: [0]=counter, [512..1536) vmean
#define WS_NEED ((WS_PART_OFF + 32ull * HH * NSLOT * PARTF) * 4ull)

typedef __bf16 bf16x8 __attribute__((ext_vector_type(8)));
typedef __bf16 bf16x4 __attribute__((ext_vector_type(4)));
typedef float f32x4 __attribute__((ext_vector_type(4)));

// Raw barrier: LDS-writes visible; outstanding GLOBAL prefetch loads stay in flight.
__device__ __forceinline__ void barw() {
  __builtin_amdgcn_sched_barrier(0);
  asm volatile("s_waitcnt lgkmcnt(0)" ::: "memory");
  __builtin_amdgcn_s_barrier();
  __builtin_amdgcn_sched_barrier(0);
}

__device__ __forceinline__ unsigned pack2(float a, float b) {
  union { __bf16 h[2]; unsigned u; } x;
  x.h[0] = (__bf16)a; x.h[1] = (__bf16)b;
  return x.u;
}

// ============================================================================
// vmean: per-head V column means (for fully-masked rows). 16 blocks, coalesced.
// ============================================================================
__global__ __launch_bounds__(256) void vmean_kernel(
    const float* __restrict__ vg, float* __restrict__ wsv)
{
  __shared__ float red[4][DDIM];
  const int h = blockIdx.x;
  const int t = threadIdx.x;
  const int d = t & 63;
  const int part = t >> 6;        // 0..3, each covers 512 rows
  float s = 0.f;
  const float* vp = vg + ((size_t)(h * NN) + part * 512) * DDIM + d;
  for (int j = 0; j < 512; ++j) s += vp[(size_t)j * DDIM];
  red[part][d] = s;
  __syncthreads();
  if (t < DDIM) {
    wsv[h * DDIM + t] =
      (red[0][t] + red[1][t] + red[2][t] + red[3][t]) * (1.0f / (float)NN);
  }
}

// ============================================================================
// R10 part: R9 work-stealing structure; DS-pressure attack:
//  - pitch-144 LDS (no XOR swizzle): <=2-way banks on all 4 access patterns
//  - packed V^T staging: thread owns 4 rows x 4 cols -> 4x ds_write_b64
//    (was 16x scalar b16, 8-way conflicted: 1024 conflict-cy/tile measured)
// ============================================================================
__global__ __launch_bounds__(256, 2) void attend_part(
    const float* __restrict__ qg, const float* __restrict__ kg,
    const float* __restrict__ vg, const unsigned int* __restrict__ maskw,
    const float* __restrict__ biasg, const float* __restrict__ prevg,
    float* __restrict__ opart, unsigned int* __restrict__ counter)
{
  __shared__ char ksh[KB * KPITCH]   __attribute__((aligned(16))); // [kv][d] bf16
  __shared__ char vsh[DDIM * KPITCH] __attribute__((aligned(16))); // [d][kv] bf16
  __shared__ int chunk_s;

  const int t    = threadIdx.x;
  const int lane = t & 63;
  const int w    = t >> 6;

  // --- mask element-width detection: 4-byte (int/float bool) vs 1-byte ---
  unsigned int mwrd = maskw[t & 255];
  const int mask4 = __syncthreads_and(mwrd == 0u || mwrd == 1u || mwrd == 0x3F800000u);

  const int llo = lane & 15;
  const int lhi = lane >> 4;
  const int cbi  = t & 15;        // staging col group: cb = cbi*4
  const int cb   = cbi << 2;
  const int rgrp = t >> 4;        // staging row group: rows rgrp*4 .. +3

  for (;;) {
    if (t == 0) chunk_s = (int)atomicAdd(counter, 1u);
    __syncthreads();
    const int c = chunk_s;
    if (c >= NCHUNK) break;
    const int h    = c & 15;
    const int rank = c >> 4;

    int qt, ci, len;
    if (rank < 120) {
      int kk = rank;
      qt = 31;
      for (;;) {
        const int nf = (qt + 1) >> 2;
        if (kk < nf) { ci = kk; len = 4; break; }
        kk -= nf; --qt;
      }
    } else {
      const int idx = rank - 120;
      const int s = 3 - (idx >> 3);
      const int j = idx & 7;
      qt  = (j << 2) + s - 1;
      ci  = j;
      len = s;
    }
    const int lo = ci << 2;
    const int hi = lo + len;
    const int qrow0 = qt * QB;
    const int qrow_g = qrow0 + w * 16 + llo;   // this lane's q-row

    // --- Q fragments (B operand), scale 1/8 folded in ---
    bf16x8 aq[2];
    {
      const float* qp = qg + ((size_t)(h * NN + qrow_g)) * DDIM + lhi * 8;
#pragma unroll
      for (int ks = 0; ks < 2; ++ks) {
        float4 f0 = *(const float4*)(qp + ks * 32);
        float4 f1 = *(const float4*)(qp + ks * 32 + 4);
        bf16x8 a;
        a[0] = (__bf16)(f0.x * 0.125f); a[1] = (__bf16)(f0.y * 0.125f);
        a[2] = (__bf16)(f0.z * 0.125f); a[3] = (__bf16)(f0.w * 0.125f);
        a[4] = (__bf16)(f1.x * 0.125f); a[5] = (__bf16)(f1.y * 0.125f);
        a[6] = (__bf16)(f1.z * 0.125f); a[7] = (__bf16)(f1.w * 0.125f);
        aq[ks] = a;
      }
    }

    f32x4 oacc[4];   // O^T frags: oacc[df][r] = O[q=llo-row][d=df*16+lhi*4+r]
#pragma unroll
    for (int i = 0; i < 4; ++i) { f32x4 z = {0.f, 0.f, 0.f, 0.f}; oacc[i] = z; }
    float m_r = -FLT_MAX, l_r = 0.f;

    // ---- prefetch registers ----
    float4 kpre[4], vpre[4];
    float4 ppre[4], bpre[4];
    uint4  mpre[4];

    auto issueKV = [&](int kv0) {
#pragma unroll
      for (int e = 0; e < 4; ++e) {
        const int row = (rgrp << 2) + e;
        const size_t gofs = ((size_t)(h * NN + kv0 + row)) * DDIM + cb;
        kpre[e] = *(const float4*)(kg + gofs);
        vpre[e] = *(const float4*)(vg + gofs);
      }
    };
    auto issuePB = [&](int kv0) {
#pragma unroll
      for (int kf = 0; kf < 4; ++kf) {
        const int col = kv0 + kf * 16 + lhi * 4;
        const size_t base = ((size_t)(h * NN) + qrow_g) * NN + col;
        ppre[kf] = *(const float4*)(prevg + base);
        bpre[kf] = *(const float4*)(biasg + base);
        const size_t midx = (size_t)qrow_g * NN + col;
        if (mask4) {
          mpre[kf] = *(const uint4*)(maskw + midx);
        } else {
          mpre[kf].x = *(const unsigned int*)((const unsigned char*)maskw + midx);
        }
      }
    };

    issueKV(lo * KB);
    issuePB(lo * KB);

    for (int tt = lo; tt < hi; ++tt) {
      const int kv0 = tt * KB;
      // ---- phase 1: stage K [kv][d] and V^T [d][kv], f32->bf16, pitch-144 ----
#pragma unroll
      for (int e = 0; e < 4; ++e) {
        const int row = (rgrp << 2) + e;
        float4 kf = kpre[e];
        bf16x4 kb4;
        kb4[0] = (__bf16)kf.x; kb4[1] = (__bf16)kf.y;
        kb4[2] = (__bf16)kf.z; kb4[3] = (__bf16)kf.w;
        *(bf16x4*)(ksh + row * KPITCH + (cb << 1)) = kb4;
      }
#pragma unroll
      for (int j = 0; j < 4; ++j) {
        bf16x4 vb4;
        vb4[0] = (__bf16)vpre[0][j]; vb4[1] = (__bf16)vpre[1][j];
        vb4[2] = (__bf16)vpre[2][j]; vb4[3] = (__bf16)vpre[3][j];
        *(bf16x4*)(vsh + (cb + j) * KPITCH + (rgrp << 3)) = vb4;
      }
      // keep current tile's softmax operands
      float4 pc[4], bc[4]; uint4 mc[4];
#pragma unroll
      for (int kf = 0; kf < 4; ++kf) { pc[kf] = ppre[kf]; bc[kf] = bpre[kf]; mc[kf] = mpre[kf]; }
      // issue next tile's loads (fly across the raw barriers)
      if (tt + 1 < hi) { issueKV(kv0 + KB); issuePB(kv0 + KB); }
      barw();

      // ---- QK^T swapped: S^T[kv][q], each lane: q=llo-row, 16 kv values ----
      f32x4 s[4];
#pragma unroll
      for (int kf = 0; kf < 4; ++kf) { f32x4 z = {0.f, 0.f, 0.f, 0.f}; s[kf] = z; }
#pragma unroll
      for (int ks = 0; ks < 2; ++ks) {
#pragma unroll
        for (int kf = 0; kf < 4; ++kf) {
          const int kvr = kf * 16 + llo;
          bf16x8 ak = *(const bf16x8*)(ksh + kvr * KPITCH + ((ks * 32 + lhi * 8) << 1));
          s[kf] = __builtin_amdgcn_mfma_f32_16x16x32_bf16(ak, aq[ks], s[kf], 0, 0, 0);
        }
      }

      // ---- softmax, fully in-register (row = q = llo; 4 lanes/row via xor16/32) ----
      float p[4][4];
      float pmax = -FLT_MAX;
#pragma unroll
      for (int kf = 0; kf < 4; ++kf) {
        float pa[4] = {pc[kf].x, pc[kf].y, pc[kf].z, pc[kf].w};
        float ba[4] = {bc[kf].x, bc[kf].y, bc[kf].z, bc[kf].w};
        unsigned mb[4];
        if (mask4) { mb[0] = mc[kf].x; mb[1] = mc[kf].y; mb[2] = mc[kf].z; mb[3] = mc[kf].w; }
        else {
          mb[0] = mc[kf].x & 0xffu; mb[1] = (mc[kf].x >> 8) & 0xffu;
          mb[2] = (mc[kf].x >> 16) & 0xffu; mb[3] = mc[kf].x >> 24;
        }
#pragma unroll
        for (int r = 0; r < 4; ++r) {
          const int j = kv0 + kf * 16 + lhi * 4 + r;
          float sv = s[kf][r] + pa[r] + ba[r];
          if (j > qrow_g || mb[r] == 0u) sv = -FLT_MAX;
          p[kf][r] = sv;
          pmax = fmaxf(pmax, sv);
        }
      }
      pmax = fmaxf(pmax, __shfl_xor(pmax, 16));
      pmax = fmaxf(pmax, __shfl_xor(pmax, 32));
      const float mnew = fmaxf(m_r, pmax);
      const float resc = __expf(m_r - mnew);   // exp(0)=1 when both -FLT_MAX (finite)
      float psum = 0.f;
#pragma unroll
      for (int kf = 0; kf < 4; ++kf)
#pragma unroll
        for (int r = 0; r < 4; ++r) {
          float e = __expf(p[kf][r] - mnew);
          p[kf][r] = e;
          psum += e;
        }
      psum += __shfl_xor(psum, 16);
      psum += __shfl_xor(psum, 32);
      l_r = l_r * resc + psum;
      m_r = mnew;
#pragma unroll
      for (int df = 0; df < 4; ++df) {
        oacc[df][0] *= resc; oacc[df][1] *= resc;
        oacc[df][2] *= resc; oacc[df][3] *= resc;
      }

      // ---- pack P -> bf16 pairs; redistribute P^T into PV B-operand; PV MFMAs ----
      unsigned U[4][2];
#pragma unroll
      for (int kf = 0; kf < 4; ++kf) {
        U[kf][0] = pack2(p[kf][0], p[kf][1]);
        U[kf][1] = pack2(p[kf][2], p[kf][3]);
      }
#pragma unroll
      for (int ks = 0; ks < 2; ++ks) {
        unsigned bb[4];
#pragma unroll
        for (int m = 0; m < 4; ++m) {
          const int src = llo + ((((lhi & 1) << 1) + (m >> 1)) << 4);
          const int va = __shfl((int)U[2 * ks + 0][m & 1], src);
          const int vb = __shfl((int)U[2 * ks + 1][m & 1], src);
          bb[m] = (lhi >> 1) ? (unsigned)vb : (unsigned)va;
        }
        union { unsigned u[4]; bf16x8 v; } pb_;
        pb_.u[0] = bb[0]; pb_.u[1] = bb[1]; pb_.u[2] = bb[2]; pb_.u[3] = bb[3];
#pragma unroll
        for (int df = 0; df < 4; ++df) {
          const int dr = df * 16 + llo;
          bf16x8 vf = *(const bf16x8*)(vsh + dr * KPITCH + ((ks * 32 + lhi * 8) << 1));
          oacc[df] = __builtin_amdgcn_mfma_f32_16x16x32_bf16(vf, pb_.v, oacc[df], 0, 0, 0);
        }
      }
      barw();   // all waves done reading ksh/vsh before next staging overwrite
    } // kv tiles

    // ---- write partial (unnormalized O, m, l) ----
    float* pb = opart + (size_t)(((h * 32 + qt) << 3) + ci) * PARTF;
    const int rowl = w * 16 + llo;
#pragma unroll
    for (int df = 0; df < 4; ++df) {
      *(f32x4*)(pb + rowl * 64 + df * 16 + lhi * 4) = oacc[df];
    }
    if (lhi == 0) {
      pb[4096 + rowl] = m_r;
      pb[4160 + rowl] = l_r;
    }
    __syncthreads();   // chunk done (stores issued); safe to reuse chunk_s/LDS
  } // chunk loop
}

// ============================================================================
// combine: merge up to 8 kv-chunk partials per (qt,h); dead rows -> vmean.
// ============================================================================
__global__ __launch_bounds__(256) void attend_combine(
    const float* __restrict__ opart, const float* __restrict__ wsv,
    float* __restrict__ outg)
{
  const int qt  = blockIdx.x;
  const int h   = blockIdx.y;
  const int t   = threadIdx.x;
  const int nch = (qt + 4) >> 2;   // ceil((qt+1)/4)
  const float* base = opart + (size_t)((h * 32 + qt) << 3) * PARTF;
  const int r  = t >> 2;          // 0..63
  const int c0 = (t & 3) * 16;    // 0,16,32,48

  float m = -FLT_MAX;
  for (int ci = 0; ci < nch; ++ci)
    m = fmaxf(m, base[(size_t)ci * PARTF + 4096 + r]);
  const bool dead = (m == -FLT_MAX);

  float l = 0.f;
  f32x4 a0 = {0,0,0,0}, a1 = {0,0,0,0}, a2 = {0,0,0,0}, a3 = {0,0,0,0};
  for (int ci = 0; ci < nch; ++ci) {
    const float* pb = base + (size_t)ci * PARTF;
    const float wgt = dead ? 0.f : __expf(pb[4096 + r] - m);
    l += pb[4160 + r] * wgt;
    const f32x4 b0 = *(const f32x4*)(pb + r * 64 + c0 + 0);
    const f32x4 b1 = *(const f32x4*)(pb + r * 64 + c0 + 4);
    const f32x4 b2 = *(const f32x4*)(pb + r * 64 + c0 + 8);
    const f32x4 b3 = *(const f32x4*)(pb + r * 64 + c0 + 12);
    a0 += b0 * wgt; a1 += b1 * wgt; a2 += b2 * wgt; a3 += b3 * wgt;
  }

  const float invl = dead ? 0.f : (1.0f / l);
  float* op = outg + ((size_t)(h * NN) + qt * QB + r) * DDIM + c0;
  const float* vm = wsv + h * DDIM + c0;
#pragma unroll
  for (int i = 0; i < 4; ++i) {
    const f32x4 ai = (i == 0) ? a0 : (i == 1) ? a1 : (i == 2) ? a2 : a3;
    float4 o;
    o.x = dead ? vm[i * 4 + 0] : ai[0] * invl;
    o.y = dead ? vm[i * 4 + 1] : ai[1] * invl;
    o.z = dead ? vm[i * 4 + 2] : ai[2] * invl;
    o.w = dead ? vm[i * 4 + 3] : ai[3] * invl;
    *(float4*)(op + i * 4) = o;
  }
}

// ============================================================================
// Fallback: single-kernel version (used only if ws_size is too small).
// ============================================================================
__global__ __launch_bounds__(256, 2) void attend_single(
    const float* __restrict__ qg, const float* __restrict__ kg,
    const float* __restrict__ vg, const unsigned int* __restrict__ maskw,
    const float* __restrict__ biasg, const float* __restrict__ prevg,
    float* __restrict__ outg)
{
  __shared__ char  ksh[KB * KPITCH]   __attribute__((aligned(16)));
  __shared__ char  vsh[DDIM * KPITCH] __attribute__((aligned(16)));
  __shared__ float vmean_s[DDIM];

  const int t    = threadIdx.x;
  const int lane = t & 63;
  const int w    = t >> 6;
  const int x    = blockIdx.x;
  const int h    = blockIdx.y;
  const int qt   = (h < 8) ? x : (31 - x);
  const int qrow0 = qt * QB;

  unsigned int mwrd = maskw[t & 255];
  const int mask4 = __syncthreads_and(mwrd == 0u || mwrd == 1u || mwrd == 0x3F800000u);

  const int llo = lane & 15;
  const int lhi = lane >> 4;
  const int cbi  = t & 15;
  const int cb   = cbi << 2;
  const int rgrp = t >> 4;
  const int qrow_g = qrow0 + w * 16 + llo;

  bf16x8 aq[2];
  {
    const float* qp = qg + ((size_t)(h * NN + qrow_g)) * DDIM + lhi * 8;
#pragma unroll
    for (int ks = 0; ks < 2; ++ks) {
      float4 f0 = *(const float4*)(qp + ks * 32);
      float4 f1 = *(const float4*)(qp + ks * 32 + 4);
      bf16x8 a;
      a[0] = (__bf16)(f0.x * 0.125f); a[1] = (__bf16)(f0.y * 0.125f);
      a[2] = (__bf16)(f0.z * 0.125f); a[3] = (__bf16)(f0.w * 0.125f);
      a[4] = (__bf16)(f1.x * 0.125f); a[5] = (__bf16)(f1.y * 0.125f);
      a[6] = (__bf16)(f1.z * 0.125f); a[7] = (__bf16)(f1.w * 0.125f);
      aq[ks] = a;
    }
  }

  f32x4 oacc[4];
#pragma unroll
  for (int i = 0; i < 4; ++i) { f32x4 z = {0.f, 0.f, 0.f, 0.f}; oacc[i] = z; }
  float m_r = -FLT_MAX, l_r = 0.f;

  float4 kpre[4], vpre[4];
  float4 ppre[4], bpre[4];
  uint4  mpre[4];

  auto issueKV = [&](int kv0) {
#pragma unroll
    for (int e = 0; e < 4; ++e) {
      const int row = (rgrp << 2) + e;
      const size_t gofs = ((size_t)(h * NN + kv0 + row)) * DDIM + cb;
      kpre[e] = *(const float4*)(kg + gofs);
      vpre[e] = *(const float4*)(vg + gofs);
    }
  };
  auto issuePB = [&](int kv0) {
#pragma unroll
    for (int kf = 0; kf < 4; ++kf) {
      const int col = kv0 + kf * 16 + lhi * 4;
      const size_t base = ((size_t)(h * NN) + qrow_g) * NN + col;
      ppre[kf] = *(const float4*)(prevg + base);
      bpre[kf] = *(const float4*)(biasg + base);
      const size_t midx = (size_t)qrow_g * NN + col;
      if (mask4) mpre[kf] = *(const uint4*)(maskw + midx);
      else       mpre[kf].x = *(const unsigned int*)((const unsigned char*)maskw + midx);
    }
  };

  const int Tq = qt + 1;
  issueKV(0);
  issuePB(0);

  for (int tt = 0; tt < Tq; ++tt) {
    const int kv0 = tt * KB;
#pragma unroll
    for (int e = 0; e < 4; ++e) {
      const int row = (rgrp << 2) + e;
      float4 kf = kpre[e];
      bf16x4 kb4;
      kb4[0] = (__bf16)kf.x; kb4[1] = (__bf16)kf.y;
      kb4[2] = (__bf16)kf.z; kb4[3] = (__bf16)kf.w;
      *(bf16x4*)(ksh + row * KPITCH + (cb << 1)) = kb4;
    }
#pragma unroll
    for (int j = 0; j < 4; ++j) {
      bf16x4 vb4;
      vb4[0] = (__bf16)vpre[0][j]; vb4[1] = (__bf16)vpre[1][j];
      vb4[2] = (__bf16)vpre[2][j]; vb4[3] = (__bf16)vpre[3][j];
      *(bf16x4*)(vsh + (cb + j) * KPITCH + (rgrp << 3)) = vb4;
    }
    float4 pc[4], bc[4]; uint4 mc[4];
#pragma unroll
    for (int kf = 0; kf < 4; ++kf) { pc[kf] = ppre[kf]; bc[kf] = bpre[kf]; mc[kf] = mpre[kf]; }
    if (tt + 1 < Tq) { issueKV(kv0 + KB); issuePB(kv0 + KB); }
    barw();

    f32x4 s[4];
#pragma unroll
    for (int kf = 0; kf < 4; ++kf) { f32x4 z = {0.f, 0.f, 0.f, 0.f}; s[kf] = z; }
#pragma unroll
    for (int ks = 0; ks < 2; ++ks) {
#pragma unroll
      for (int kf = 0; kf < 4; ++kf) {
        const int kvr = kf * 16 + llo;
        bf16x8 ak = *(const bf16x8*)(ksh + kvr * KPITCH + ((ks * 32 + lhi * 8) << 1));
        s[kf] = __builtin_amdgcn_mfma_f32_16x16x32_bf16(ak, aq[ks], s[kf], 0, 0, 0);
      }
    }

    float p[4][4];
    float pmax = -FLT_MAX;
#pragma unroll
    for (int kf = 0; kf < 4; ++kf) {
      float pa[4] = {pc[kf].x, pc[kf].y, pc[kf].z, pc[kf].w};
      float ba[4] = {bc[kf].x, bc[kf].y, bc[kf].z, bc[kf].w};
      unsigned mb[4];
      if (mask4) { mb[0] = mc[kf].x; mb[1] = mc[kf].y; mb[2] = mc[kf].z; mb[3] = mc[kf].w; }
      else {
        mb[0] = mc[kf].x & 0xffu; mb[1] = (mc[kf].x >> 8) & 0xffu;
        mb[2] = (mc[kf].x >> 16) & 0xffu; mb[3] = mc[kf].x >> 24;
      }
#pragma unroll
      for (int r = 0; r < 4; ++r) {
        const int j = kv0 + kf * 16 + lhi * 4 + r;
        float sv = s[kf][r] + pa[r] + ba[r];
        if (j > qrow_g || mb[r] == 0u) sv = -FLT_MAX;
        p[kf][r] = sv;
        pmax = fmaxf(pmax, sv);
      }
    }
    pmax = fmaxf(pmax, __shfl_xor(pmax, 16));
    pmax = fmaxf(pmax, __shfl_xor(pmax, 32));
    const float mnew = fmaxf(m_r, pmax);
    const float resc = __expf(m_r - mnew);
    float psum = 0.f;
#pragma unroll
    for (int kf = 0; kf < 4; ++kf)
#pragma unroll
      for (int r = 0; r < 4; ++r) {
        float e = __expf(p[kf][r] - mnew);
        p[kf][r] = e;
        psum += e;
      }
    psum += __shfl_xor(psum, 16);
    psum += __shfl_xor(psum, 32);
    l_r = l_r * resc + psum;
    m_r = mnew;
#pragma unroll
    for (int df = 0; df < 4; ++df) {
      oacc[df][0] *= resc; oacc[df][1] *= resc;
      oacc[df][2] *= resc; oacc[df][3] *= resc;
    }

    unsigned U[4][2];
#pragma unroll
    for (int kf = 0; kf < 4; ++kf) {
      U[kf][0] = pack2(p[kf][0], p[kf][1]);
      U[kf][1] = pack2(p[kf][2], p[kf][3]);
    }
#pragma unroll
    for (int ks = 0; ks < 2; ++ks) {
      unsigned bb[4];
#pragma unroll
      for (int m = 0; m < 4; ++m) {
        const int src = llo + ((((lhi & 1) << 1) + (m >> 1)) << 4);
        const int va = __shfl((int)U[2 * ks + 0][m & 1], src);
        const int vb = __shfl((int)U[2 * ks + 1][m & 1], src);
        bb[m] = (lhi >> 1) ? (unsigned)vb : (unsigned)va;
      }
      union { unsigned u[4]; bf16x8 v; } pb_;
      pb_.u[0] = bb[0]; pb_.u[1] = bb[1]; pb_.u[2] = bb[2]; pb_.u[3] = bb[3];
#pragma unroll
      for (int df = 0; df < 4; ++df) {
        const int dr = df * 16 + llo;
        bf16x8 vf = *(const bf16x8*)(vsh + dr * KPITCH + ((ks * 32 + lhi * 8) << 1));
        oacc[df] = __builtin_amdgcn_mfma_f32_16x16x32_bf16(vf, pb_.v, oacc[df], 0, 0, 0);
      }
    }
    barw();
  }

  const int anyNeed = __syncthreads_or(m_r == -FLT_MAX);
  if (anyNeed) {
    if (t < DDIM) vmean_s[t] = 0.f;
    __syncthreads();
    {
      const int d = t & 63, part = t >> 6;
      float sacc = 0.f;
      for (int j = part; j < NN; j += 4) sacc += vg[((size_t)(h * NN + j)) * DDIM + d];
      atomicAdd(&vmean_s[d], sacc);
    }
    __syncthreads();
    if (t < DDIM) vmean_s[t] *= (1.0f / (float)NN);
    __syncthreads();
  }
  const float invl = 1.0f / l_r;
  const bool dead = (m_r == -FLT_MAX);
#pragma unroll
  for (int df = 0; df < 4; ++df) {
    const int dbase = df * 16 + lhi * 4;
    float4 o;
    o.x = dead ? vmean_s[dbase + 0] : oacc[df][0] * invl;
    o.y = dead ? vmean_s[dbase + 1] : oacc[df][1] * invl;
    o.z = dead ? vmean_s[dbase + 2] : oacc[df][2] * invl;
    o.w = dead ? vmean_s[dbase + 3] : oacc[df][3] * invl;
    *(float4*)(outg + ((size_t)(h * NN) + qrow_g) * DDIM + dbase) = o;
  }
}

extern "C" void kernel_launch(void* const* d_in, const int* in_sizes, int n_in,
                              void* d_out, int out_size, void* d_ws, size_t ws_size,
                              hipStream_t stream) {
  (void)in_sizes; (void)n_in; (void)out_size;
  const float* q    = (const float*)d_in[0];
  const float* k    = (const float*)d_in[1];
  const float* v    = (const float*)d_in[2];
  const unsigned int* mask = (const unsigned int*)d_in[3];
  const float* bias = (const float*)d_in[4];
  const float* prev = (const float*)d_in[5];
  float* out = (float*)d_out;

  if (ws_size >= WS_NEED) {
    float* wsf = (float*)d_ws;
    unsigned int* counter = (unsigned int*)wsf;          // [0]
    float* wsv   = wsf + 512;                            // vmean: 16*64 floats
    float* opart = wsf + WS_PART_OFF;                    // partials
    hipMemsetAsync(counter, 0, 4, stream);
    vmean_kernel<<<dim3(HH), 256, 0, stream>>>(v, wsv);
    attend_part<<<dim3(1024), 256, 0, stream>>>(q, k, v, mask, bias, prev, opart, counter);
    attend_combine<<<dim3(32, HH), 256, 0, stream>>>(opart, wsv, out);
  } else {
    attend_single<<<dim3(32, HH), 256, 0, stream>>>(q, k, v, mask, bias, prev, out);
  }
}